// Round 12
// baseline (869.957 us; speedup 1.0000x reference)
//
#include <hip/hip_runtime.h>
#include <hip/hip_fp16.h>

#define N_NODES 50000
#define N_EDGES 800000
#define SLOPE 0.15f

typedef unsigned short u16;
typedef __attribute__((ext_vector_type(8))) __bf16 bf16x8;
typedef __attribute__((ext_vector_type(4))) float f32x4;

static __device__ __forceinline__ float leaky(float v) { return v > 0.f ? v : SLOPE * v; }

// split fp32 into hi/lo bf16 pair: v ~= hi + lo, residual ~2^-17 relative
static __device__ __forceinline__ ushort2 split_bf(float v) {
    __bf16 h = (__bf16)v;
    float hf = (float)h;
    __bf16 l = (__bf16)(v - hf);
    ushort2 r;
    r.x = __builtin_bit_cast(unsigned short, h);
    r.y = __builtin_bit_cast(unsigned short, l);
    return r;
}

// async global->LDS 16B: HW writes lane's data to (wave-uniform lds base) + lane*16
static __device__ __forceinline__ void async_load16(const u16* g, u16* l) {
    __builtin_amdgcn_global_load_lds(
        (const __attribute__((address_space(1))) unsigned int*)g,
        (__attribute__((address_space(3))) unsigned int*)l, 16, 0, 0);
}

// ---------------- merged prep: edge count | x split | weight transpose+split ----------
__global__ void k_prep(const int* __restrict__ dst, int* __restrict__ cnt,
                       const float* __restrict__ x, u16* __restrict__ xh, u16* __restrict__ xl,
                       const float* __restrict__ W1l, const float* __restrict__ W1r,
                       const float* __restrict__ W2l, const float* __restrict__ W2r,
                       const float* __restrict__ W3l, const float* __restrict__ W3r,
                       u16* w1lh, u16* w1ll, u16* w1rh, u16* w1rl,
                       u16* w2ch, u16* w2cl, u16* w3ch, u16* w3cl) {
    int b = blockIdx.x, tid = threadIdx.x;
    if (b < 3125) {
        int e = b * 256 + tid;
        if (e < N_EDGES) atomicAdd(&cnt[dst[e]], 1);
        return;
    }
    b -= 3125;
    if (b < 6250) {
        int i = b * 256 + tid;
        if (i >= N_NODES * 32) return;
        float4 v = ((const float4*)x)[i];
        ushort2 s0 = split_bf(v.x), s1 = split_bf(v.y), s2 = split_bf(v.z), s3 = split_bf(v.w);
        ((ushort4*)xh)[i] = make_ushort4(s0.x, s1.x, s2.x, s3.x);
        ((ushort4*)xl)[i] = make_ushort4(s0.y, s1.y, s2.y, s3.y);
        return;
    }
    b -= 6250;
    const float* W; u16 *oh, *ol; int K, N;
    if (b < 256)       { W = W1l; oh = w1lh; ol = w1ll; K = 128; N = 512; }
    else if (b < 512)  { W = W1r; oh = w1rh; ol = w1rl; K = 128; N = 512; b -= 256; }
    else if (b < 1024) { W = W2l; oh = w2ch; ol = w2cl; K = 512; N = 256; b -= 512; }
    else if (b < 1536) { W = W2r; oh = w2ch + 256 * 512; ol = w2cl + 256 * 512; K = 512; N = 256; b -= 1024; }
    else if (b < 1600) { W = W3l; oh = w3ch; ol = w3cl; K = 256; N = 64; b -= 1536; }
    else               { W = W3r; oh = w3ch + 64 * 256; ol = w3cl + 64 * 256; K = 256; N = 64; b -= 1600; }
    int i = b * 256 + tid;
    if (i >= K * N) return;
    int k = i / N, n = i - k * N;
    ushort2 s = split_bf(W[i]);
    size_t o = (size_t)n * K + k;   // W^T [N][K]
    oh[o] = s.x;
    ol[o] = s.y;
}

// multi-block scan, stage 1
__global__ __launch_bounds__(1024) void k_scan1(const int* __restrict__ cnt,
                                                int* __restrict__ offs,
                                                int* __restrict__ bsum) {
    __shared__ int wsum[16];
    int tid = threadIdx.x, lane = tid & 63, wv = tid >> 6;
    int i = blockIdx.x * 1024 + tid;
    int orig = (i < N_NODES) ? cnt[i] : 0;
    int v = orig;
#pragma unroll
    for (int d = 1; d < 64; d <<= 1) {
        int t = __shfl_up(v, d, 64);
        if (lane >= d) v += t;
    }
    if (lane == 63) wsum[wv] = v;
    __syncthreads();
    if (wv == 0) {
        int s = (lane < 16) ? wsum[lane] : 0;
#pragma unroll
        for (int d = 1; d < 16; d <<= 1) {
            int t = __shfl_up(s, d, 64);
            if (lane >= d) s += t;
        }
        if (lane < 16) wsum[lane] = s;
        if (lane == 15) bsum[blockIdx.x] = s;
    }
    __syncthreads();
    int wpre = (wv == 0) ? 0 : wsum[wv - 1];
    if (i < N_NODES) offs[i] = v + wpre - orig;
}

__global__ void k_scan2(int* __restrict__ bsum, int nb) {
    int lane = threadIdx.x;
    int v = (lane < nb) ? bsum[lane] : 0;
    int s = v;
#pragma unroll
    for (int d = 1; d < 64; d <<= 1) {
        int t = __shfl_up(s, d, 64);
        if (lane >= d) s += t;
    }
    if (lane < nb) bsum[lane] = s - v;
}

__global__ void k_scan3(const int* __restrict__ cnt, int* __restrict__ offs,
                        int* __restrict__ cursor, float* __restrict__ inv,
                        const int* __restrict__ bsum) {
    int i = blockIdx.x * 256 + threadIdx.x;
    if (i >= N_NODES) return;
    int c = cnt[i];
    int o = offs[i] + bsum[i >> 10];
    offs[i] = o;
    cursor[i] = o;
    inv[i] = 1.0f / (float)(c > 1 ? c : 1);
    if (i == 0) offs[N_NODES] = N_EDGES;
}

__global__ void k_fill(const int* __restrict__ src, const int* __restrict__ dst,
                       int* __restrict__ cursor, int* __restrict__ ssrc) {
    int e = blockIdx.x * 256 + threadIdx.x;
    if (e < N_EDGES) {
        int pos = atomicAdd(&cursor[dst[e]], 1);
        ssrc[pos] = src[e];
    }
}

// ---------------- mean aggregation (fp32 table, column-split) ----------------
// EPI: 1 = split planes out; 3 = leaky(y+a+bias) -> f32
template <int D, int STRIDE, int U, int EPI>
__global__ __launch_bounds__(256) void k_agg(const float* __restrict__ tbl,
                                             const int* __restrict__ offs,
                                             const int* __restrict__ ssrc,
                                             const float* __restrict__ inv,
                                             const float* __restrict__ y,
                                             const float* __restrict__ bias,
                                             float* __restrict__ outf,
                                             u16* __restrict__ oh, u16* __restrict__ ol) {
    constexpr int G = 256 / D;
    constexpr int LPG = 64 / G;
    int wid = (blockIdx.x * 256 + threadIdx.x) >> 6;
    if (wid >= N_NODES) return;
    const int coff = blockIdx.y * D;
    int lane = threadIdx.x & 63;
    int eg = lane / LPG;
    int cl = lane % LPG;
    int beg = offs[wid], end = offs[wid + 1];
    float4 acc[U];
#pragma unroll
    for (int j = 0; j < U; ++j) acc[j] = make_float4(0.f, 0.f, 0.f, 0.f);
    for (int e = beg + eg; e < end; e += U * G) {
        int idx[U]; float msk[U];
#pragma unroll
        for (int j = 0; j < U; ++j) {
            int ee = e + j * G;
            bool ok = ee < end;
            idx[j] = ssrc[ok ? ee : e];
            msk[j] = ok ? 1.f : 0.f;
        }
#pragma unroll
        for (int j = 0; j < U; ++j) {
            const float4 t = *(const float4*)(tbl + (size_t)idx[j] * STRIDE + coff + cl * 4);
            acc[j].x = fmaf(t.x, msk[j], acc[j].x);
            acc[j].y = fmaf(t.y, msk[j], acc[j].y);
            acc[j].z = fmaf(t.z, msk[j], acc[j].z);
            acc[j].w = fmaf(t.w, msk[j], acc[j].w);
        }
    }
#pragma unroll
    for (int j = 1; j < U; ++j) {
        acc[0].x += acc[j].x; acc[0].y += acc[j].y;
        acc[0].z += acc[j].z; acc[0].w += acc[j].w;
    }
    float a0 = acc[0].x, a1 = acc[0].y, a2 = acc[0].z, a3 = acc[0].w;
#pragma unroll
    for (int m = LPG; m < 64; m <<= 1) {
        a0 += __shfl_xor(a0, m, 64);
        a1 += __shfl_xor(a1, m, 64);
        a2 += __shfl_xor(a2, m, 64);
        a3 += __shfl_xor(a3, m, 64);
    }
    float wv = inv[wid];
    a0 *= wv; a1 *= wv; a2 *= wv; a3 *= wv;
    if (eg != 0) return;
    const size_t ob = (size_t)wid * STRIDE + coff + cl * 4;
    if (EPI == 1) {
        ushort2 s0 = split_bf(a0), s1 = split_bf(a1), s2 = split_bf(a2), s3 = split_bf(a3);
        *(ushort4*)(oh + ob) = make_ushort4(s0.x, s1.x, s2.x, s3.x);
        *(ushort4*)(ol + ob) = make_ushort4(s0.y, s1.y, s2.y, s3.y);
    } else {
        float4 yv = *(const float4*)(y + ob);
        float4 bv = *(const float4*)(bias + coff + cl * 4);
        *(float4*)(outf + ob) = make_float4(
            leaky(a0 + yv.x + bv.x), leaky(a1 + yv.y + bv.y),
            leaky(a2 + yv.z + bv.z), leaky(a3 + yv.w + bv.w));
    }
}

// ---------------- z2 aggregation (fp16 table [N][256]) + h2 epilogue ----------------
// 4 column chunks of 64; 8 lanes/edge x 8 halves; U=4; h2 = leaky(S z2 + y2 + b2) -> planes
__global__ __launch_bounds__(256) void k_aggh(const u16* __restrict__ tbl,
                                              const int* __restrict__ offs,
                                              const int* __restrict__ ssrc,
                                              const float* __restrict__ inv,
                                              const float* __restrict__ y,
                                              const float* __restrict__ bias,
                                              u16* __restrict__ oh, u16* __restrict__ ol) {
    constexpr int U = 4;
    int wid = (blockIdx.x * 256 + threadIdx.x) >> 6;
    if (wid >= N_NODES) return;
    const int coff = blockIdx.y * 64;
    int lane = threadIdx.x & 63;
    int eg = lane >> 3;     // 8 edges per iteration
    int cl = lane & 7;      // 8 lanes per edge, 8 halves (16B) each
    int beg = offs[wid], end = offs[wid + 1];
    float acc[8] = {};
    for (int e = beg + eg; e < end; e += U * 8) {
        int idx[U]; float msk[U];
#pragma unroll
        for (int j = 0; j < U; ++j) {
            int ee = e + j * 8;
            bool ok = ee < end;
            idx[j] = ssrc[ok ? ee : e];
            msk[j] = ok ? 1.f : 0.f;
        }
#pragma unroll
        for (int j = 0; j < U; ++j) {
            uint4 rv = *(const uint4*)(tbl + (size_t)idx[j] * 256 + coff + cl * 8);
            const __half2* hp = (const __half2*)&rv;
#pragma unroll
            for (int t = 0; t < 4; ++t) {
                float2 f = __half22float2(hp[t]);
                acc[t * 2 + 0] = fmaf(f.x, msk[j], acc[t * 2 + 0]);
                acc[t * 2 + 1] = fmaf(f.y, msk[j], acc[t * 2 + 1]);
            }
        }
    }
#pragma unroll
    for (int m = 8; m < 64; m <<= 1)
#pragma unroll
        for (int t = 0; t < 8; ++t) acc[t] += __shfl_xor(acc[t], m, 64);
    if (eg != 0) return;
    float wv = inv[wid];
    const size_t ob = (size_t)wid * 256 + coff + cl * 8;
    float4 y0 = *(const float4*)(y + ob);
    float4 y1 = *(const float4*)(y + ob + 4);
    float4 b0 = *(const float4*)(bias + coff + cl * 8);
    float4 b1 = *(const float4*)(bias + coff + cl * 8 + 4);
    float v[8];
    v[0] = leaky(acc[0] * wv + y0.x + b0.x);
    v[1] = leaky(acc[1] * wv + y0.y + b0.y);
    v[2] = leaky(acc[2] * wv + y0.z + b0.z);
    v[3] = leaky(acc[3] * wv + y0.w + b0.w);
    v[4] = leaky(acc[4] * wv + y1.x + b1.x);
    v[5] = leaky(acc[5] * wv + y1.y + b1.y);
    v[6] = leaky(acc[6] * wv + y1.z + b1.z);
    v[7] = leaky(acc[7] * wv + y1.w + b1.w);
    ushort2 s[8];
#pragma unroll
    for (int t = 0; t < 8; ++t) s[t] = split_bf(v[t]);
    *(ushort4*)(oh + ob)     = make_ushort4(s[0].x, s[1].x, s[2].x, s[3].x);
    *(ushort4*)(oh + ob + 4) = make_ushort4(s[4].x, s[5].x, s[6].x, s[7].x);
    *(ushort4*)(ol + ob)     = make_ushort4(s[0].y, s[1].y, s[2].y, s[3].y);
    *(ushort4*)(ol + ob + 4) = make_ushort4(s[4].y, s[5].y, s[6].y, s[7].y);
}

// ---------------- split-bf16 MFMA GEMM: 128x128 tile, single-buffer, 5 blocks/CU ------
// mode1: 0 = f32 -> out1f; 1 = split planes -> out1h/out1l; 2 = fp16 -> out1h
__global__ __launch_bounds__(256, 5) void k_gemm_s(
    int M, int nct,
    const u16* __restrict__ A1h, const u16* __restrict__ A1l,
    const u16* __restrict__ B1h, const u16* __restrict__ B1l, int K1,
    const u16* __restrict__ A2h, const u16* __restrict__ A2l,
    const u16* __restrict__ B2h, const u16* __restrict__ B2l, int K2,
    const float* __restrict__ bias, int act, int colsplit, int mode1,
    float* __restrict__ out1f, u16* __restrict__ out1h, u16* __restrict__ out1l, int n1,
    float* __restrict__ out2f, int n2) {
    __shared__ u16 Ash[4096], Asl[4096], Bsh[4096], Bsl[4096];
    const int tid = threadIdx.x;
    const int lane = tid & 63;
    const int w = tid >> 6;
    const int wm = w & 1, wn = w >> 1;
    const int fr = lane & 15;
    const int q = lane >> 4;

    const int mT = (M + 127) >> 7;
    const int lin = blockIdx.x;
    const int grp = lin / (8 * nct);
    const int idx = lin - grp * (8 * nct);
    const int ct = idx >> 3;
    const int s8 = idx & 7;
    const int rowt = grp * 8 + s8;
    if (rowt >= mT) return;
    const int brow = rowt * 128;
    const int bcol = ct * 128;

    const int T1 = K1 >> 5, T = T1 + (K2 >> 5);

    const int c0 = (w * 2 + 0) * 64 + lane;
    const int c1 = (w * 2 + 1) * 64 + lane;
    const int r0 = c0 >> 2, g0 = (c0 & 3) ^ ((r0 >> 1) & 3);
    const int r1 = c1 >> 2, g1 = (c1 & 3) ^ ((r1 >> 1) & 3);
    int ar0 = brow + r0; if (ar0 >= M) ar0 = M - 1;
    int ar1 = brow + r1; if (ar1 >= M) ar1 = M - 1;
    const int br0 = bcol + r0, br1 = bcol + r1;
    const int ub0 = (w * 2 + 0) * 512;
    const int ub1 = (w * 2 + 1) * 512;

    f32x4 acc[4][4] = {};

    for (int kt = 0; kt < T; ++kt) {
        const u16 *Ah, *Al, *Bh, *Bl; int K, k0;
        if (kt < T1) { Ah = A1h; Al = A1l; Bh = B1h; Bl = B1l; K = K1; k0 = kt * 32; }
        else         { Ah = A2h; Al = A2l; Bh = B2h; Bl = B2l; K = K2; k0 = (kt - T1) * 32; }
        __syncthreads();
        {
            size_t ga0 = (size_t)ar0 * K + k0 + g0 * 8;
            size_t ga1 = (size_t)ar1 * K + k0 + g1 * 8;
            size_t gb0 = (size_t)br0 * K + k0 + g0 * 8;
            size_t gb1 = (size_t)br1 * K + k0 + g1 * 8;
            async_load16(Ah + ga0, &Ash[ub0]);
            async_load16(Ah + ga1, &Ash[ub1]);
            async_load16(Al + ga0, &Asl[ub0]);
            async_load16(Al + ga1, &Asl[ub1]);
            async_load16(Bh + gb0, &Bsh[ub0]);
            async_load16(Bh + gb1, &Bsh[ub1]);
            async_load16(Bl + gb0, &Bsl[ub0]);
            async_load16(Bl + gb1, &Bsl[ub1]);
        }
        __syncthreads();
        bf16x8 fah[4], fal[4], fbh[4], fbl[4];
#pragma unroll
        for (int rt = 0; rt < 4; ++rt) {
            int row = wm * 64 + rt * 16 + fr;
            int ad = row * 32 + ((q ^ ((row >> 1) & 3)) * 8);
            fah[rt] = __builtin_bit_cast(bf16x8, *(const uint4*)&Ash[ad]);
            fal[rt] = __builtin_bit_cast(bf16x8, *(const uint4*)&Asl[ad]);
        }
#pragma unroll
        for (int ctf = 0; ctf < 4; ++ctf) {
            int row = wn * 64 + ctf * 16 + fr;
            int ad = row * 32 + ((q ^ ((row >> 1) & 3)) * 8);
            fbh[ctf] = __builtin_bit_cast(bf16x8, *(const uint4*)&Bsh[ad]);
            fbl[ctf] = __builtin_bit_cast(bf16x8, *(const uint4*)&Bsl[ad]);
        }
#pragma unroll
        for (int rt = 0; rt < 4; ++rt)
#pragma unroll
            for (int ctf = 0; ctf < 4; ++ctf) {
                acc[rt][ctf] = __builtin_amdgcn_mfma_f32_16x16x32_bf16(fah[rt], fbh[ctf], acc[rt][ctf], 0, 0, 0);
                acc[rt][ctf] = __builtin_amdgcn_mfma_f32_16x16x32_bf16(fah[rt], fbl[ctf], acc[rt][ctf], 0, 0, 0);
                acc[rt][ctf] = __builtin_amdgcn_mfma_f32_16x16x32_bf16(fal[rt], fbh[ctf], acc[rt][ctf], 0, 0, 0);
            }
    }

#pragma unroll
    for (int rt = 0; rt < 4; ++rt) {
        int rowb = brow + wm * 64 + rt * 16 + q * 4;
#pragma unroll
        for (int ctf = 0; ctf < 4; ++ctf) {
            int col = bcol + wn * 64 + ctf * 16 + fr;
            float b = bias ? bias[col] : 0.f;
#pragma unroll
            for (int r = 0; r < 4; ++r) {
                int row = rowb + r;
                if (row >= M) continue;
                float v = acc[rt][ctf][r] + b;
                if (act) v = leaky(v);
                if (col < colsplit) {
                    if (mode1 == 0) {
                        out1f[(size_t)row * n1 + col] = v;
                    } else if (mode1 == 1) {
                        ushort2 s = split_bf(v);
                        out1h[(size_t)row * n1 + col] = s.x;
                        out1l[(size_t)row * n1 + col] = s.y;
                    } else {
                        __half hv = __float2half(v);
                        out1h[(size_t)row * n1 + col] = __builtin_bit_cast(u16, hv);
                    }
                } else {
                    out2f[(size_t)row * n2 + (col - colsplit)] = v;
                }
            }
        }
    }
}

// ---------------- fused head: h3 -> pre_fc -> leaky(fc1) -> fc2 ------
__global__ __launch_bounds__(256) void k_head(const float* __restrict__ h3,
                                              const float* __restrict__ Wp, const float* __restrict__ bp,
                                              const float* __restrict__ Wf1, const float* __restrict__ bf1,
                                              const float* __restrict__ Wf2, const float* __restrict__ bf2,
                                              float* __restrict__ out) {
    __shared__ float sWp[64 * 32], sW1[32 * 32], sW2[32 * 2];
    __shared__ float sbp[32], sb1[32], sb2[2];
    int tid = threadIdx.x;
    for (int i = tid; i < 64 * 32; i += 256) sWp[i] = Wp[i];
    for (int i = tid; i < 32 * 32; i += 256) sW1[i] = Wf1[i];
    for (int i = tid; i < 64; i += 256) sW2[i] = Wf2[i];
    if (tid < 32) { sbp[tid] = bp[tid]; sb1[tid] = bf1[tid]; }
    if (tid < 2) sb2[tid] = bf2[tid];
    __syncthreads();
    int row = blockIdx.x * 256 + tid;
    if (row >= N_NODES) return;
    const float4* h4v = (const float4*)(h3 + (size_t)row * 64);
    float xr[64];
#pragma unroll
    for (int i = 0; i < 16; ++i) {
        float4 v = h4v[i];
        xr[i * 4 + 0] = v.x; xr[i * 4 + 1] = v.y;
        xr[i * 4 + 2] = v.z; xr[i * 4 + 3] = v.w;
    }
    float h4[32];
    for (int o = 0; o < 32; ++o) {
        float s = sbp[o];
#pragma unroll
        for (int i = 0; i < 64; ++i) s += xr[i] * sWp[i * 32 + o];
        h4[o] = s;
    }
    float h5[32];
    for (int o = 0; o < 32; ++o) {
        float s = sb1[o];
#pragma unroll
        for (int i = 0; i < 32; ++i) s += h4[i] * sW1[i * 32 + o];
        h5[o] = leaky(s);
    }
#pragma unroll
    for (int o = 0; o < 2; ++o) {
        float s = sb2[o];
#pragma unroll
        for (int i = 0; i < 32; ++i) s += h5[i] * sW2[i * 2 + o];
        out[(size_t)row * 2 + o] = s;
    }
}

// ---------------- launch ----------------
extern "C" void kernel_launch(void* const* d_in, const int* in_sizes, int n_in,
                              void* d_out, int out_size, void* d_ws, size_t ws_size,
                              hipStream_t stream) {
    const float* x   = (const float*)d_in[0];
    const int*   ei  = (const int*)d_in[1];
    const float* W1l = (const float*)d_in[5];
    const float* b1  = (const float*)d_in[6];
    const float* W1r = (const float*)d_in[7];
    const float* W2l = (const float*)d_in[8];
    const float* b2  = (const float*)d_in[9];
    const float* W2r = (const float*)d_in[10];
    const float* W3l = (const float*)d_in[11];
    const float* b3  = (const float*)d_in[12];
    const float* W3r = (const float*)d_in[13];
    const float* Wp  = (const float*)d_in[14];
    const float* bp  = (const float*)d_in[15];
    const float* Wf1 = (const float*)d_in[16];
    const float* bf1 = (const float*)d_in[17];
    const float* Wf2 = (const float*)d_in[18];
    const float* bf2 = (const float*)d_in[19];
    float* out = (float*)d_out;
    (void)in_sizes; (void)n_in; (void)out_size; (void)ws_size;

    const int* src = ei;
    const int* dst = ei + N_EDGES;

    char* base = (char*)d_ws;
    size_t off = 0;
    auto alloc = [&](size_t bytes) -> void* {
        void* r = base + off;
        off = (off + bytes + 255) & ~(size_t)255;
        return r;
    };
    const size_t NN = N_NODES;
    int*   cnt    = (int*)alloc(NN * 4);
    int*   offs   = (int*)alloc((NN + 1) * 4);
    int*   cursor = (int*)alloc(NN * 4);
    float* inv    = (float*)alloc(NN * 4);
    int*   bsum   = (int*)alloc(64 * 4);
    int*   ssrc   = (int*)alloc((size_t)N_EDGES * 4);
    u16* w1lh = (u16*)alloc(128 * 512 * 2); u16* w1ll = (u16*)alloc(128 * 512 * 2);
    u16* w1rh = (u16*)alloc(128 * 512 * 2); u16* w1rl = (u16*)alloc(128 * 512 * 2);
    u16* w2ch = (u16*)alloc(512 * 512 * 2); u16* w2cl = (u16*)alloc(512 * 512 * 2);
    u16* w3ch = (u16*)alloc(128 * 256 * 2); u16* w3cl = (u16*)alloc(128 * 256 * 2);

    // Live-range-aliased regions (~205 MB)
    char* regA = (char*)alloc(NN * 256 * 4);       // xh|xl|axh|axl -> z2h(fp16) -> h3
    char* regB = (char*)alloc(NN * 512 * 2 * 2);   // h1h|h1l -> h2h|h2l
    char* regD = (char*)alloc(NN * 256 * 4);       // y2 -> z3|y3

    u16* xh  = (u16*)regA;
    u16* xl  = xh + NN * 128;
    u16* axh = xl + NN * 128;
    u16* axl = axh + NN * 128;
    u16* h1h = (u16*)regB;
    u16* h1l = h1h + NN * 512;
    u16* z2h = (u16*)regA;                         // fp16 z2 [N][256] (x/aggX dead)
    u16* h2h = (u16*)regB;                         // aggh epilogue out (h1 dead)
    u16* h2l = h2h + NN * 256;
    float* y2f = (float*)regD;                     // read inside aggh epilogue (then dead)
    float* z3f = (float*)regD;                     // L3 GEMM out (y2 dead)
    float* y3f = z3f + NN * 64;
    float* h3f = (float*)regA;                     // agg3 epilogue out (z2h dead)

    // CSR + prep
    hipMemsetAsync(cnt, 0, NN * 4, stream);
    k_prep<<<3125 + 6250 + 1664, 256, 0, stream>>>(dst, cnt, x, xh, xl,
        W1l, W1r, W2l, W2r, W3l, W3r,
        w1lh, w1ll, w1rh, w1rl, w2ch, w2cl, w3ch, w3cl);
    const int nb = (N_NODES + 1023) / 1024;   // 49
    k_scan1<<<nb, 1024, 0, stream>>>(cnt, offs, bsum);
    k_scan2<<<1, 64, 0, stream>>>(bsum, nb);
    k_scan3<<<(N_NODES + 255) / 256, 256, 0, stream>>>(cnt, offs, cursor, inv, bsum);
    k_fill<<<(N_EDGES + 255) / 256, 256, 0, stream>>>(src, dst, cursor, ssrc);

    const int aggGrid = (N_NODES + 3) / 4;             // 12500
    const int mT = (N_NODES + 127) / 128;              // 391
    const int grid4 = ((mT + 7) / 8) * 32;             // nct=4
    const int grid1 = ((mT + 7) / 8) * 8;              // nct=1

    // layer 1: aggX = S x (split, 2 chunks); h1 = leaky(aggX@W1l + x@W1r + b1)
    k_agg<64, 128, 8, 1><<<dim3(aggGrid, 2), 256, 0, stream>>>(
        x, offs, ssrc, inv, nullptr, nullptr, nullptr, axh, axl);
    k_gemm_s<<<grid4, 256, 0, stream>>>(N_NODES, 4,
        axh, axl, w1lh, w1ll, 128, xh, xl, w1rh, w1rl, 128,
        b1, 1, 512, 1, nullptr, h1h, h1l, 512, nullptr, 0);

    // layer 2: [z2(fp16)|y2(f32)] = h1 @ [W2l|W2r]; aggh: h2 = leaky(S z2 + y2 + b2)
    k_gemm_s<<<grid4, 256, 0, stream>>>(N_NODES, 4,
        h1h, h1l, w2ch, w2cl, 512, nullptr, nullptr, nullptr, nullptr, 0,
        nullptr, 0, 256, 2, nullptr, z2h, nullptr, 256, y2f, 256);
    k_aggh<<<dim3(aggGrid, 4), 256, 0, stream>>>(
        z2h, offs, ssrc, inv, y2f, b2, h2h, h2l);

    // layer 3: [z3|y3] = h2 @ [W3l|W3r]; agg3 epilogue: h3 = leaky(S z3 + y3 + b3)
    k_gemm_s<<<grid1, 256, 0, stream>>>(N_NODES, 1,
        h2h, h2l, w3ch, w3cl, 256, nullptr, nullptr, nullptr, nullptr, 0,
        nullptr, 0, 64, 0, z3f, nullptr, nullptr, 64, y3f, 64);
    k_agg<32, 64, 8, 3><<<dim3(aggGrid, 2), 256, 0, stream>>>(
        z3f, offs, ssrc, inv, y3f, b3, h3f, nullptr, nullptr);

    // head: h3 -> pre_fc -> leaky(fc1) -> fc2
    k_head<<<(N_NODES + 255) / 256, 256, 0, stream>>>(h3f,
        Wp, bp, Wf1, bf1, Wf2, bf2, out);
}

// Round 13
// 618.252 us; speedup vs baseline: 1.4071x; 1.4071x over previous
//
#include <hip/hip_runtime.h>
#include <hip/hip_fp16.h>

#define N_NODES 50000
#define N_EDGES 800000
#define SLOPE 0.15f

typedef unsigned short u16;
typedef __attribute__((ext_vector_type(8))) __bf16 bf16x8;
typedef __attribute__((ext_vector_type(4))) float f32x4;

static __device__ __forceinline__ float leaky(float v) { return v > 0.f ? v : SLOPE * v; }

// split fp32 into hi/lo bf16 pair: v ~= hi + lo, residual ~2^-17 relative
static __device__ __forceinline__ ushort2 split_bf(float v) {
    __bf16 h = (__bf16)v;
    float hf = (float)h;
    __bf16 l = (__bf16)(v - hf);
    ushort2 r;
    r.x = __builtin_bit_cast(unsigned short, h);
    r.y = __builtin_bit_cast(unsigned short, l);
    return r;
}

// async global->LDS 16B: HW writes lane's data to (wave-uniform lds base) + lane*16
static __device__ __forceinline__ void async_load16(const u16* g, u16* l) {
    __builtin_amdgcn_global_load_lds(
        (const __attribute__((address_space(1))) unsigned int*)g,
        (__attribute__((address_space(3))) unsigned int*)l, 16, 0, 0);
}

// ---------------- merged prep: edge count | x split | weight transpose+split ----------
__global__ void k_prep(const int* __restrict__ dst, int* __restrict__ cnt,
                       const float* __restrict__ x, u16* __restrict__ xh, u16* __restrict__ xl,
                       const float* __restrict__ W1l, const float* __restrict__ W1r,
                       const float* __restrict__ W2l, const float* __restrict__ W2r,
                       const float* __restrict__ W3l, const float* __restrict__ W3r,
                       u16* w1lh, u16* w1ll, u16* w1rh, u16* w1rl,
                       u16* w2ch, u16* w2cl, u16* w3ch, u16* w3cl) {
    int b = blockIdx.x, tid = threadIdx.x;
    if (b < 3125) {
        int e = b * 256 + tid;
        if (e < N_EDGES) atomicAdd(&cnt[dst[e]], 1);
        return;
    }
    b -= 3125;
    if (b < 6250) {
        int i = b * 256 + tid;
        if (i >= N_NODES * 32) return;
        float4 v = ((const float4*)x)[i];
        ushort2 s0 = split_bf(v.x), s1 = split_bf(v.y), s2 = split_bf(v.z), s3 = split_bf(v.w);
        ((ushort4*)xh)[i] = make_ushort4(s0.x, s1.x, s2.x, s3.x);
        ((ushort4*)xl)[i] = make_ushort4(s0.y, s1.y, s2.y, s3.y);
        return;
    }
    b -= 6250;
    const float* W; u16 *oh, *ol; int K, N;
    if (b < 256)       { W = W1l; oh = w1lh; ol = w1ll; K = 128; N = 512; }
    else if (b < 512)  { W = W1r; oh = w1rh; ol = w1rl; K = 128; N = 512; b -= 256; }
    else if (b < 1024) { W = W2l; oh = w2ch; ol = w2cl; K = 512; N = 256; b -= 512; }
    else if (b < 1536) { W = W2r; oh = w2ch + 256 * 512; ol = w2cl + 256 * 512; K = 512; N = 256; b -= 1024; }
    else if (b < 1600) { W = W3l; oh = w3ch; ol = w3cl; K = 256; N = 64; b -= 1536; }
    else               { W = W3r; oh = w3ch + 64 * 256; ol = w3cl + 64 * 256; K = 256; N = 64; b -= 1600; }
    int i = b * 256 + tid;
    if (i >= K * N) return;
    int k = i / N, n = i - k * N;
    ushort2 s = split_bf(W[i]);
    size_t o = (size_t)n * K + k;   // W^T [N][K]
    oh[o] = s.x;
    ol[o] = s.y;
}

// multi-block scan, stage 1
__global__ __launch_bounds__(1024) void k_scan1(const int* __restrict__ cnt,
                                                int* __restrict__ offs,
                                                int* __restrict__ bsum) {
    __shared__ int wsum[16];
    int tid = threadIdx.x, lane = tid & 63, wv = tid >> 6;
    int i = blockIdx.x * 1024 + tid;
    int orig = (i < N_NODES) ? cnt[i] : 0;
    int v = orig;
#pragma unroll
    for (int d = 1; d < 64; d <<= 1) {
        int t = __shfl_up(v, d, 64);
        if (lane >= d) v += t;
    }
    if (lane == 63) wsum[wv] = v;
    __syncthreads();
    if (wv == 0) {
        int s = (lane < 16) ? wsum[lane] : 0;
#pragma unroll
        for (int d = 1; d < 16; d <<= 1) {
            int t = __shfl_up(s, d, 64);
            if (lane >= d) s += t;
        }
        if (lane < 16) wsum[lane] = s;
        if (lane == 15) bsum[blockIdx.x] = s;
    }
    __syncthreads();
    int wpre = (wv == 0) ? 0 : wsum[wv - 1];
    if (i < N_NODES) offs[i] = v + wpre - orig;
}

__global__ void k_scan2(int* __restrict__ bsum, int nb) {
    int lane = threadIdx.x;
    int v = (lane < nb) ? bsum[lane] : 0;
    int s = v;
#pragma unroll
    for (int d = 1; d < 64; d <<= 1) {
        int t = __shfl_up(s, d, 64);
        if (lane >= d) s += t;
    }
    if (lane < nb) bsum[lane] = s - v;
}

__global__ void k_scan3(const int* __restrict__ cnt, int* __restrict__ offs,
                        int* __restrict__ cursor, float* __restrict__ inv,
                        const int* __restrict__ bsum) {
    int i = blockIdx.x * 256 + threadIdx.x;
    if (i >= N_NODES) return;
    int c = cnt[i];
    int o = offs[i] + bsum[i >> 10];
    offs[i] = o;
    cursor[i] = o;
    inv[i] = 1.0f / (float)(c > 1 ? c : 1);
    if (i == 0) offs[N_NODES] = N_EDGES;
}

__global__ void k_fill(const int* __restrict__ src, const int* __restrict__ dst,
                       int* __restrict__ cursor, int* __restrict__ ssrc) {
    int e = blockIdx.x * 256 + threadIdx.x;
    if (e < N_EDGES) {
        int pos = atomicAdd(&cursor[dst[e]], 1);
        ssrc[pos] = src[e];
    }
}

// ---------------- mean aggregation (fp32 table, column-split) ----------------
// EPI: 1 = split planes out; 3 = leaky(y+a+bias) -> f32
template <int D, int STRIDE, int U, int EPI>
__global__ __launch_bounds__(256) void k_agg(const float* __restrict__ tbl,
                                             const int* __restrict__ offs,
                                             const int* __restrict__ ssrc,
                                             const float* __restrict__ inv,
                                             const float* __restrict__ y,
                                             const float* __restrict__ bias,
                                             float* __restrict__ outf,
                                             u16* __restrict__ oh, u16* __restrict__ ol) {
    constexpr int G = 256 / D;
    constexpr int LPG = 64 / G;
    int wid = (blockIdx.x * 256 + threadIdx.x) >> 6;
    if (wid >= N_NODES) return;
    const int coff = blockIdx.y * D;
    int lane = threadIdx.x & 63;
    int eg = lane / LPG;
    int cl = lane % LPG;
    int beg = offs[wid], end = offs[wid + 1];
    float4 acc[U];
#pragma unroll
    for (int j = 0; j < U; ++j) acc[j] = make_float4(0.f, 0.f, 0.f, 0.f);
    for (int e = beg + eg; e < end; e += U * G) {
        int idx[U]; float msk[U];
#pragma unroll
        for (int j = 0; j < U; ++j) {
            int ee = e + j * G;
            bool ok = ee < end;
            idx[j] = ssrc[ok ? ee : e];
            msk[j] = ok ? 1.f : 0.f;
        }
#pragma unroll
        for (int j = 0; j < U; ++j) {
            const float4 t = *(const float4*)(tbl + (size_t)idx[j] * STRIDE + coff + cl * 4);
            acc[j].x = fmaf(t.x, msk[j], acc[j].x);
            acc[j].y = fmaf(t.y, msk[j], acc[j].y);
            acc[j].z = fmaf(t.z, msk[j], acc[j].z);
            acc[j].w = fmaf(t.w, msk[j], acc[j].w);
        }
    }
#pragma unroll
    for (int j = 1; j < U; ++j) {
        acc[0].x += acc[j].x; acc[0].y += acc[j].y;
        acc[0].z += acc[j].z; acc[0].w += acc[j].w;
    }
    float a0 = acc[0].x, a1 = acc[0].y, a2 = acc[0].z, a3 = acc[0].w;
#pragma unroll
    for (int m = LPG; m < 64; m <<= 1) {
        a0 += __shfl_xor(a0, m, 64);
        a1 += __shfl_xor(a1, m, 64);
        a2 += __shfl_xor(a2, m, 64);
        a3 += __shfl_xor(a3, m, 64);
    }
    float wv = inv[wid];
    a0 *= wv; a1 *= wv; a2 *= wv; a3 *= wv;
    if (eg != 0) return;
    const size_t ob = (size_t)wid * STRIDE + coff + cl * 4;
    if (EPI == 1) {
        ushort2 s0 = split_bf(a0), s1 = split_bf(a1), s2 = split_bf(a2), s3 = split_bf(a3);
        *(ushort4*)(oh + ob) = make_ushort4(s0.x, s1.x, s2.x, s3.x);
        *(ushort4*)(ol + ob) = make_ushort4(s0.y, s1.y, s2.y, s3.y);
    } else {
        float4 yv = *(const float4*)(y + ob);
        float4 bv = *(const float4*)(bias + coff + cl * 4);
        *(float4*)(outf + ob) = make_float4(
            leaky(a0 + yv.x + bv.x), leaky(a1 + yv.y + bv.y),
            leaky(a2 + yv.z + bv.z), leaky(a3 + yv.w + bv.w));
    }
}

// ---------------- z2 aggregation (fp16 table [N][256]) + h2 epilogue ----------------
__global__ __launch_bounds__(256) void k_aggh(const u16* __restrict__ tbl,
                                              const int* __restrict__ offs,
                                              const int* __restrict__ ssrc,
                                              const float* __restrict__ inv,
                                              const float* __restrict__ y,
                                              const float* __restrict__ bias,
                                              u16* __restrict__ oh, u16* __restrict__ ol) {
    constexpr int U = 4;
    int wid = (blockIdx.x * 256 + threadIdx.x) >> 6;
    if (wid >= N_NODES) return;
    const int coff = blockIdx.y * 64;
    int lane = threadIdx.x & 63;
    int eg = lane >> 3;     // 8 edges per iteration
    int cl = lane & 7;      // 8 lanes per edge, 8 halves (16B) each
    int beg = offs[wid], end = offs[wid + 1];
    float acc[8] = {};
    for (int e = beg + eg; e < end; e += U * 8) {
        int idx[U]; float msk[U];
#pragma unroll
        for (int j = 0; j < U; ++j) {
            int ee = e + j * 8;
            bool ok = ee < end;
            idx[j] = ssrc[ok ? ee : e];
            msk[j] = ok ? 1.f : 0.f;
        }
#pragma unroll
        for (int j = 0; j < U; ++j) {
            uint4 rv = *(const uint4*)(tbl + (size_t)idx[j] * 256 + coff + cl * 8);
            const __half2* hp = (const __half2*)&rv;
#pragma unroll
            for (int t = 0; t < 4; ++t) {
                float2 f = __half22float2(hp[t]);
                acc[t * 2 + 0] = fmaf(f.x, msk[j], acc[t * 2 + 0]);
                acc[t * 2 + 1] = fmaf(f.y, msk[j], acc[t * 2 + 1]);
            }
        }
    }
#pragma unroll
    for (int m = 8; m < 64; m <<= 1)
#pragma unroll
        for (int t = 0; t < 8; ++t) acc[t] += __shfl_xor(acc[t], m, 64);
    if (eg != 0) return;
    float wv = inv[wid];
    const size_t ob = (size_t)wid * 256 + coff + cl * 8;
    float4 y0 = *(const float4*)(y + ob);
    float4 y1 = *(const float4*)(y + ob + 4);
    float4 b0 = *(const float4*)(bias + coff + cl * 8);
    float4 b1 = *(const float4*)(bias + coff + cl * 8 + 4);
    float v[8];
    v[0] = leaky(acc[0] * wv + y0.x + b0.x);
    v[1] = leaky(acc[1] * wv + y0.y + b0.y);
    v[2] = leaky(acc[2] * wv + y0.z + b0.z);
    v[3] = leaky(acc[3] * wv + y0.w + b0.w);
    v[4] = leaky(acc[4] * wv + y1.x + b1.x);
    v[5] = leaky(acc[5] * wv + y1.y + b1.y);
    v[6] = leaky(acc[6] * wv + y1.z + b1.z);
    v[7] = leaky(acc[7] * wv + y1.w + b1.w);
    ushort2 s[8];
#pragma unroll
    for (int t = 0; t < 8; ++t) s[t] = split_bf(v[t]);
    *(ushort4*)(oh + ob)     = make_ushort4(s[0].x, s[1].x, s[2].x, s[3].x);
    *(ushort4*)(oh + ob + 4) = make_ushort4(s[4].x, s[5].x, s[6].x, s[7].x);
    *(ushort4*)(ol + ob)     = make_ushort4(s[0].y, s[1].y, s[2].y, s[3].y);
    *(ushort4*)(ol + ob + 4) = make_ushort4(s[4].y, s[5].y, s[6].y, s[7].y);
}

// ---------------- split-bf16 MFMA GEMM: 128x128 tile, single-buffer, 4 blocks/CU ------
// (4 blocks/CU is the validated point: 5 forces VGPR 64->48 and spills the
//  accumulator to scratch — round-12's 496 MB WRITE_SIZE regression.)
// mode1: 0 = f32 -> out1f; 1 = split planes -> out1h/out1l; 2 = fp16 -> out1h
__global__ __launch_bounds__(256, 4) void k_gemm_s(
    int M, int nct,
    const u16* __restrict__ A1h, const u16* __restrict__ A1l,
    const u16* __restrict__ B1h, const u16* __restrict__ B1l, int K1,
    const u16* __restrict__ A2h, const u16* __restrict__ A2l,
    const u16* __restrict__ B2h, const u16* __restrict__ B2l, int K2,
    const float* __restrict__ bias, int act, int colsplit, int mode1,
    float* __restrict__ out1f, u16* __restrict__ out1h, u16* __restrict__ out1l, int n1,
    float* __restrict__ out2f, int n2) {
    __shared__ u16 Ash[4096], Asl[4096], Bsh[4096], Bsl[4096];
    const int tid = threadIdx.x;
    const int lane = tid & 63;
    const int w = tid >> 6;
    const int wm = w & 1, wn = w >> 1;
    const int fr = lane & 15;
    const int q = lane >> 4;

    const int mT = (M + 127) >> 7;
    const int lin = blockIdx.x;
    const int grp = lin / (8 * nct);
    const int idx = lin - grp * (8 * nct);
    const int ct = idx >> 3;
    const int s8 = idx & 7;
    const int rowt = grp * 8 + s8;
    if (rowt >= mT) return;
    const int brow = rowt * 128;
    const int bcol = ct * 128;

    const int T1 = K1 >> 5, T = T1 + (K2 >> 5);

    const int c0 = (w * 2 + 0) * 64 + lane;
    const int c1 = (w * 2 + 1) * 64 + lane;
    const int r0 = c0 >> 2, g0 = (c0 & 3) ^ ((r0 >> 1) & 3);
    const int r1 = c1 >> 2, g1 = (c1 & 3) ^ ((r1 >> 1) & 3);
    int ar0 = brow + r0; if (ar0 >= M) ar0 = M - 1;
    int ar1 = brow + r1; if (ar1 >= M) ar1 = M - 1;
    const int br0 = bcol + r0, br1 = bcol + r1;
    const int ub0 = (w * 2 + 0) * 512;
    const int ub1 = (w * 2 + 1) * 512;

    f32x4 acc[4][4] = {};

    for (int kt = 0; kt < T; ++kt) {
        const u16 *Ah, *Al, *Bh, *Bl; int K, k0;
        if (kt < T1) { Ah = A1h; Al = A1l; Bh = B1h; Bl = B1l; K = K1; k0 = kt * 32; }
        else         { Ah = A2h; Al = A2l; Bh = B2h; Bl = B2l; K = K2; k0 = (kt - T1) * 32; }
        __syncthreads();
        {
            size_t ga0 = (size_t)ar0 * K + k0 + g0 * 8;
            size_t ga1 = (size_t)ar1 * K + k0 + g1 * 8;
            size_t gb0 = (size_t)br0 * K + k0 + g0 * 8;
            size_t gb1 = (size_t)br1 * K + k0 + g1 * 8;
            async_load16(Ah + ga0, &Ash[ub0]);
            async_load16(Ah + ga1, &Ash[ub1]);
            async_load16(Al + ga0, &Asl[ub0]);
            async_load16(Al + ga1, &Asl[ub1]);
            async_load16(Bh + gb0, &Bsh[ub0]);
            async_load16(Bh + gb1, &Bsh[ub1]);
            async_load16(Bl + gb0, &Bsl[ub0]);
            async_load16(Bl + gb1, &Bsl[ub1]);
        }
        __syncthreads();
        bf16x8 fah[4], fal[4], fbh[4], fbl[4];
#pragma unroll
        for (int rt = 0; rt < 4; ++rt) {
            int row = wm * 64 + rt * 16 + fr;
            int ad = row * 32 + ((q ^ ((row >> 1) & 3)) * 8);
            fah[rt] = __builtin_bit_cast(bf16x8, *(const uint4*)&Ash[ad]);
            fal[rt] = __builtin_bit_cast(bf16x8, *(const uint4*)&Asl[ad]);
        }
#pragma unroll
        for (int ctf = 0; ctf < 4; ++ctf) {
            int row = wn * 64 + ctf * 16 + fr;
            int ad = row * 32 + ((q ^ ((row >> 1) & 3)) * 8);
            fbh[ctf] = __builtin_bit_cast(bf16x8, *(const uint4*)&Bsh[ad]);
            fbl[ctf] = __builtin_bit_cast(bf16x8, *(const uint4*)&Bsl[ad]);
        }
#pragma unroll
        for (int rt = 0; rt < 4; ++rt)
#pragma unroll
            for (int ctf = 0; ctf < 4; ++ctf) {
                acc[rt][ctf] = __builtin_amdgcn_mfma_f32_16x16x32_bf16(fah[rt], fbh[ctf], acc[rt][ctf], 0, 0, 0);
                acc[rt][ctf] = __builtin_amdgcn_mfma_f32_16x16x32_bf16(fah[rt], fbl[ctf], acc[rt][ctf], 0, 0, 0);
                acc[rt][ctf] = __builtin_amdgcn_mfma_f32_16x16x32_bf16(fal[rt], fbh[ctf], acc[rt][ctf], 0, 0, 0);
            }
    }

#pragma unroll
    for (int rt = 0; rt < 4; ++rt) {
        int rowb = brow + wm * 64 + rt * 16 + q * 4;
#pragma unroll
        for (int ctf = 0; ctf < 4; ++ctf) {
            int col = bcol + wn * 64 + ctf * 16 + fr;
            float b = bias ? bias[col] : 0.f;
#pragma unroll
            for (int r = 0; r < 4; ++r) {
                int row = rowb + r;
                if (row >= M) continue;
                float v = acc[rt][ctf][r] + b;
                if (act) v = leaky(v);
                if (col < colsplit) {
                    if (mode1 == 0) {
                        out1f[(size_t)row * n1 + col] = v;
                    } else if (mode1 == 1) {
                        ushort2 s = split_bf(v);
                        out1h[(size_t)row * n1 + col] = s.x;
                        out1l[(size_t)row * n1 + col] = s.y;
                    } else {
                        __half hv = __float2half(v);
                        out1h[(size_t)row * n1 + col] = __builtin_bit_cast(u16, hv);
                    }
                } else {
                    out2f[(size_t)row * n2 + (col - colsplit)] = v;
                }
            }
        }
    }
}

// ---------------- fused head: h3 -> pre_fc -> leaky(fc1) -> fc2 ------
__global__ __launch_bounds__(256) void k_head(const float* __restrict__ h3,
                                              const float* __restrict__ Wp, const float* __restrict__ bp,
                                              const float* __restrict__ Wf1, const float* __restrict__ bf1,
                                              const float* __restrict__ Wf2, const float* __restrict__ bf2,
                                              float* __restrict__ out) {
    __shared__ float sWp[64 * 32], sW1[32 * 32], sW2[32 * 2];
    __shared__ float sbp[32], sb1[32], sb2[2];
    int tid = threadIdx.x;
    for (int i = tid; i < 64 * 32; i += 256) sWp[i] = Wp[i];
    for (int i = tid; i < 32 * 32; i += 256) sW1[i] = Wf1[i];
    for (int i = tid; i < 64; i += 256) sW2[i] = Wf2[i];
    if (tid < 32) { sbp[tid] = bp[tid]; sb1[tid] = bf1[tid]; }
    if (tid < 2) sb2[tid] = bf2[tid];
    __syncthreads();
    int row = blockIdx.x * 256 + tid;
    if (row >= N_NODES) return;
    const float4* h4v = (const float4*)(h3 + (size_t)row * 64);
    float xr[64];
#pragma unroll
    for (int i = 0; i < 16; ++i) {
        float4 v = h4v[i];
        xr[i * 4 + 0] = v.x; xr[i * 4 + 1] = v.y;
        xr[i * 4 + 2] = v.z; xr[i * 4 + 3] = v.w;
    }
    float h4[32];
    for (int o = 0; o < 32; ++o) {
        float s = sbp[o];
#pragma unroll
        for (int i = 0; i < 64; ++i) s += xr[i] * sWp[i * 32 + o];
        h4[o] = s;
    }
    float h5[32];
    for (int o = 0; o < 32; ++o) {
        float s = sb1[o];
#pragma unroll
        for (int i = 0; i < 32; ++i) s += h4[i] * sW1[i * 32 + o];
        h5[o] = leaky(s);
    }
#pragma unroll
    for (int o = 0; o < 2; ++o) {
        float s = sb2[o];
#pragma unroll
        for (int i = 0; i < 32; ++i) s += h5[i] * sW2[i * 2 + o];
        out[(size_t)row * 2 + o] = s;
    }
}

// ---------------- launch ----------------
extern "C" void kernel_launch(void* const* d_in, const int* in_sizes, int n_in,
                              void* d_out, int out_size, void* d_ws, size_t ws_size,
                              hipStream_t stream) {
    const float* x   = (const float*)d_in[0];
    const int*   ei  = (const int*)d_in[1];
    const float* W1l = (const float*)d_in[5];
    const float* b1  = (const float*)d_in[6];
    const float* W1r = (const float*)d_in[7];
    const float* W2l = (const float*)d_in[8];
    const float* b2  = (const float*)d_in[9];
    const float* W2r = (const float*)d_in[10];
    const float* W3l = (const float*)d_in[11];
    const float* b3  = (const float*)d_in[12];
    const float* W3r = (const float*)d_in[13];
    const float* Wp  = (const float*)d_in[14];
    const float* bp  = (const float*)d_in[15];
    const float* Wf1 = (const float*)d_in[16];
    const float* bf1 = (const float*)d_in[17];
    const float* Wf2 = (const float*)d_in[18];
    const float* bf2 = (const float*)d_in[19];
    float* out = (float*)d_out;
    (void)in_sizes; (void)n_in; (void)out_size; (void)ws_size;

    const int* src = ei;
    const int* dst = ei + N_EDGES;

    char* base = (char*)d_ws;
    size_t off = 0;
    auto alloc = [&](size_t bytes) -> void* {
        void* r = base + off;
        off = (off + bytes + 255) & ~(size_t)255;
        return r;
    };
    const size_t NN = N_NODES;
    int*   cnt    = (int*)alloc(NN * 4);
    int*   offs   = (int*)alloc((NN + 1) * 4);
    int*   cursor = (int*)alloc(NN * 4);
    float* inv    = (float*)alloc(NN * 4);
    int*   bsum   = (int*)alloc(64 * 4);
    int*   ssrc   = (int*)alloc((size_t)N_EDGES * 4);
    u16* w1lh = (u16*)alloc(128 * 512 * 2); u16* w1ll = (u16*)alloc(128 * 512 * 2);
    u16* w1rh = (u16*)alloc(128 * 512 * 2); u16* w1rl = (u16*)alloc(128 * 512 * 2);
    u16* w2ch = (u16*)alloc(512 * 512 * 2); u16* w2cl = (u16*)alloc(512 * 512 * 2);
    u16* w3ch = (u16*)alloc(128 * 256 * 2); u16* w3cl = (u16*)alloc(128 * 256 * 2);

    // Live-range-aliased regions (~205 MB)
    char* regA = (char*)alloc(NN * 256 * 4);       // xh|xl|axh|axl -> z2h(fp16) -> h3
    char* regB = (char*)alloc(NN * 512 * 2 * 2);   // h1h|h1l -> h2h|h2l
    char* regD = (char*)alloc(NN * 256 * 4);       // y2 -> z3|y3

    u16* xh  = (u16*)regA;
    u16* xl  = xh + NN * 128;
    u16* axh = xl + NN * 128;
    u16* axl = axh + NN * 128;
    u16* h1h = (u16*)regB;
    u16* h1l = h1h + NN * 512;
    u16* z2h = (u16*)regA;                         // fp16 z2 [N][256] (x/aggX dead)
    u16* h2h = (u16*)regB;                         // aggh epilogue out (h1 dead)
    u16* h2l = h2h + NN * 256;
    float* y2f = (float*)regD;                     // read inside aggh epilogue (then dead)
    float* z3f = (float*)regD;                     // L3 GEMM out (y2 dead)
    float* y3f = z3f + NN * 64;
    float* h3f = (float*)regA;                     // agg3 epilogue out (z2h dead)

    // CSR + prep
    hipMemsetAsync(cnt, 0, NN * 4, stream);
    k_prep<<<3125 + 6250 + 1664, 256, 0, stream>>>(dst, cnt, x, xh, xl,
        W1l, W1r, W2l, W2r, W3l, W3r,
        w1lh, w1ll, w1rh, w1rl, w2ch, w2cl, w3ch, w3cl);
    const int nb = (N_NODES + 1023) / 1024;   // 49
    k_scan1<<<nb, 1024, 0, stream>>>(cnt, offs, bsum);
    k_scan2<<<1, 64, 0, stream>>>(bsum, nb);
    k_scan3<<<(N_NODES + 255) / 256, 256, 0, stream>>>(cnt, offs, cursor, inv, bsum);
    k_fill<<<(N_EDGES + 255) / 256, 256, 0, stream>>>(src, dst, cursor, ssrc);

    const int aggGrid = (N_NODES + 3) / 4;             // 12500
    const int mT = (N_NODES + 127) / 128;              // 391
    const int grid4 = ((mT + 7) / 8) * 32;             // nct=4
    const int grid1 = ((mT + 7) / 8) * 8;              // nct=1

    // layer 1: aggX = S x (split, 2 chunks); h1 = leaky(aggX@W1l + x@W1r + b1)
    k_agg<64, 128, 8, 1><<<dim3(aggGrid, 2), 256, 0, stream>>>(
        x, offs, ssrc, inv, nullptr, nullptr, nullptr, axh, axl);
    k_gemm_s<<<grid4, 256, 0, stream>>>(N_NODES, 4,
        axh, axl, w1lh, w1ll, 128, xh, xl, w1rh, w1rl, 128,
        b1, 1, 512, 1, nullptr, h1h, h1l, 512, nullptr, 0);

    // layer 2: [z2(fp16)|y2(f32)] = h1 @ [W2l|W2r]; aggh: h2 = leaky(S z2 + y2 + b2)
    k_gemm_s<<<grid4, 256, 0, stream>>>(N_NODES, 4,
        h1h, h1l, w2ch, w2cl, 512, nullptr, nullptr, nullptr, nullptr, 0,
        nullptr, 0, 256, 2, nullptr, z2h, nullptr, 256, y2f, 256);
    k_aggh<<<dim3(aggGrid, 4), 256, 0, stream>>>(
        z2h, offs, ssrc, inv, y2f, b2, h2h, h2l);

    // layer 3: [z3|y3] = h2 @ [W3l|W3r]; agg3 epilogue: h3 = leaky(S z3 + y3 + b3)
    k_gemm_s<<<grid1, 256, 0, stream>>>(N_NODES, 1,
        h2h, h2l, w3ch, w3cl, 256, nullptr, nullptr, nullptr, nullptr, 0,
        nullptr, 0, 64, 0, z3f, nullptr, nullptr, 64, y3f, 64);
    k_agg<32, 64, 8, 3><<<dim3(aggGrid, 2), 256, 0, stream>>>(
        z3f, offs, ssrc, inv, y3f, b3, h3f, nullptr, nullptr);

    // head: h3 -> pre_fc -> leaky(fc1) -> fc2
    k_head<<<(N_NODES + 255) / 256, 256, 0, stream>>>(h3f,
        Wp, bp, Wf1, bf1, Wf2, bf2, out);
}

// Round 14
// 589.593 us; speedup vs baseline: 1.4755x; 1.0486x over previous
//
#include <hip/hip_runtime.h>
#include <hip/hip_fp16.h>

#define N_NODES 50000
#define N_EDGES 800000
#define SLOPE 0.15f

typedef unsigned short u16;
typedef __attribute__((ext_vector_type(8))) __bf16 bf16x8;
typedef __attribute__((ext_vector_type(4))) float f32x4;

static __device__ __forceinline__ float leaky(float v) { return v > 0.f ? v : SLOPE * v; }

static __device__ __forceinline__ float bf2f(u16 b) {
    return __builtin_bit_cast(float, (unsigned)b << 16);
}

// split fp32 into hi/lo bf16 pair: v ~= hi + lo, residual ~2^-17 relative
static __device__ __forceinline__ ushort2 split_bf(float v) {
    __bf16 h = (__bf16)v;
    float hf = (float)h;
    __bf16 l = (__bf16)(v - hf);
    ushort2 r;
    r.x = __builtin_bit_cast(unsigned short, h);
    r.y = __builtin_bit_cast(unsigned short, l);
    return r;
}

// async global->LDS 16B: HW writes lane's data to (wave-uniform lds base) + lane*16
static __device__ __forceinline__ void async_load16(const u16* g, u16* l) {
    __builtin_amdgcn_global_load_lds(
        (const __attribute__((address_space(1))) unsigned int*)g,
        (__attribute__((address_space(3))) unsigned int*)l, 16, 0, 0);
}

// ---------------- merged prep: edge count | x split | weight transpose+split ----------
__global__ void k_prep(const int* __restrict__ dst, int* __restrict__ cnt,
                       const float* __restrict__ x, u16* __restrict__ xh, u16* __restrict__ xl,
                       const float* __restrict__ W1l, const float* __restrict__ W1r,
                       const float* __restrict__ W2l, const float* __restrict__ W2r,
                       const float* __restrict__ W3l, const float* __restrict__ W3r,
                       u16* w1lh, u16* w1ll, u16* w1rh, u16* w1rl,
                       u16* w2ch, u16* w2cl, u16* w3ch, u16* w3cl) {
    int b = blockIdx.x, tid = threadIdx.x;
    if (b < 3125) {
        int e = b * 256 + tid;
        if (e < N_EDGES) atomicAdd(&cnt[dst[e]], 1);
        return;
    }
    b -= 3125;
    if (b < 6250) {
        int i = b * 256 + tid;
        if (i >= N_NODES * 32) return;
        float4 v = ((const float4*)x)[i];
        ushort2 s0 = split_bf(v.x), s1 = split_bf(v.y), s2 = split_bf(v.z), s3 = split_bf(v.w);
        ((ushort4*)xh)[i] = make_ushort4(s0.x, s1.x, s2.x, s3.x);
        ((ushort4*)xl)[i] = make_ushort4(s0.y, s1.y, s2.y, s3.y);
        return;
    }
    b -= 6250;
    const float* W; u16 *oh, *ol; int K, N;
    if (b < 256)       { W = W1l; oh = w1lh; ol = w1ll; K = 128; N = 512; }
    else if (b < 512)  { W = W1r; oh = w1rh; ol = w1rl; K = 128; N = 512; b -= 256; }
    else if (b < 1024) { W = W2l; oh = w2ch; ol = w2cl; K = 512; N = 256; b -= 512; }
    else if (b < 1536) { W = W2r; oh = w2ch + 256 * 512; ol = w2cl + 256 * 512; K = 512; N = 256; b -= 1024; }
    else if (b < 1600) { W = W3l; oh = w3ch; ol = w3cl; K = 256; N = 64; b -= 1536; }
    else               { W = W3r; oh = w3ch + 64 * 256; ol = w3cl + 64 * 256; K = 256; N = 64; b -= 1600; }
    int i = b * 256 + tid;
    if (i >= K * N) return;
    int k = i / N, n = i - k * N;
    ushort2 s = split_bf(W[i]);
    size_t o = (size_t)n * K + k;   // W^T [N][K]
    oh[o] = s.x;
    ol[o] = s.y;
}

// multi-block scan, stage 1
__global__ __launch_bounds__(1024) void k_scan1(const int* __restrict__ cnt,
                                                int* __restrict__ offs,
                                                int* __restrict__ bsum) {
    __shared__ int wsum[16];
    int tid = threadIdx.x, lane = tid & 63, wv = tid >> 6;
    int i = blockIdx.x * 1024 + tid;
    int orig = (i < N_NODES) ? cnt[i] : 0;
    int v = orig;
#pragma unroll
    for (int d = 1; d < 64; d <<= 1) {
        int t = __shfl_up(v, d, 64);
        if (lane >= d) v += t;
    }
    if (lane == 63) wsum[wv] = v;
    __syncthreads();
    if (wv == 0) {
        int s = (lane < 16) ? wsum[lane] : 0;
#pragma unroll
        for (int d = 1; d < 16; d <<= 1) {
            int t = __shfl_up(s, d, 64);
            if (lane >= d) s += t;
        }
        if (lane < 16) wsum[lane] = s;
        if (lane == 15) bsum[blockIdx.x] = s;
    }
    __syncthreads();
    int wpre = (wv == 0) ? 0 : wsum[wv - 1];
    if (i < N_NODES) offs[i] = v + wpre - orig;
}

// stage 2+3 merged: each block redundantly scans the (<=64) block sums in wave 0,
// then applies offsets and emits cursor + inv.
__global__ void k_scan3(const int* __restrict__ cnt, int* __restrict__ offs,
                        int* __restrict__ cursor, float* __restrict__ inv,
                        const int* __restrict__ bsum, int nb) {
    __shared__ int sb[64];
    int tid = threadIdx.x;
    if (tid < 64) {
        int v = (tid < nb) ? bsum[tid] : 0;
        int s = v;
#pragma unroll
        for (int d = 1; d < 64; d <<= 1) {
            int t = __shfl_up(s, d, 64);
            if (tid >= d) s += t;
        }
        sb[tid] = s - v;   // exclusive prefix of block sums
    }
    __syncthreads();
    int i = blockIdx.x * 256 + tid;
    if (i >= N_NODES) return;
    int c = cnt[i];
    int o = offs[i] + sb[i >> 10];
    offs[i] = o;
    cursor[i] = o;
    inv[i] = 1.0f / (float)(c > 1 ? c : 1);
    if (i == 0) offs[N_NODES] = N_EDGES;
}

__global__ void k_fill(const int* __restrict__ src, const int* __restrict__ dst,
                       int* __restrict__ cursor, int* __restrict__ ssrc) {
    int e = blockIdx.x * 256 + threadIdx.x;
    if (e < N_EDGES) {
        int pos = atomicAdd(&cursor[dst[e]], 1);
        ssrc[pos] = src[e];
    }
}

// ---------------- x aggregation (bf16 split-plane table [N][128]) -> split out --------
// blockIdx.y picks one of 2 column chunks of 64; 8 lanes/edge x 8 bf16 per plane.
__global__ __launch_bounds__(256) void k_aggb(const u16* __restrict__ th,
                                              const u16* __restrict__ tl,
                                              const int* __restrict__ offs,
                                              const int* __restrict__ ssrc,
                                              const float* __restrict__ inv,
                                              u16* __restrict__ oh, u16* __restrict__ ol) {
    constexpr int U = 4;
    int wid = (blockIdx.x * 256 + threadIdx.x) >> 6;
    if (wid >= N_NODES) return;
    const int coff = blockIdx.y * 64;
    int lane = threadIdx.x & 63;
    int eg = lane >> 3;     // 8 edges per iteration
    int cl = lane & 7;      // 8 lanes per edge
    int beg = offs[wid], end = offs[wid + 1];
    float acc[8] = {};
    for (int e = beg + eg; e < end; e += U * 8) {
        int idx[U]; float msk[U];
#pragma unroll
        for (int j = 0; j < U; ++j) {
            int ee = e + j * 8;
            bool ok = ee < end;
            idx[j] = ssrc[ok ? ee : e];
            msk[j] = ok ? 1.f : 0.f;
        }
#pragma unroll
        for (int j = 0; j < U; ++j) {
            size_t ga = (size_t)idx[j] * 128 + coff + cl * 8;
            uint4 rh = *(const uint4*)(th + ga);
            uint4 rl = *(const uint4*)(tl + ga);
            const u16* ph = (const u16*)&rh;
            const u16* pl = (const u16*)&rl;
#pragma unroll
            for (int t = 0; t < 8; ++t)
                acc[t] = fmaf(bf2f(ph[t]) + bf2f(pl[t]), msk[j], acc[t]);
        }
    }
#pragma unroll
    for (int m = 8; m < 64; m <<= 1)
#pragma unroll
        for (int t = 0; t < 8; ++t) acc[t] += __shfl_xor(acc[t], m, 64);
    if (eg != 0) return;
    float wv = inv[wid];
    const size_t ob = (size_t)wid * 128 + coff + cl * 8;
    ushort2 s[8];
#pragma unroll
    for (int t = 0; t < 8; ++t) s[t] = split_bf(acc[t] * wv);
    *(ushort4*)(oh + ob)     = make_ushort4(s[0].x, s[1].x, s[2].x, s[3].x);
    *(ushort4*)(oh + ob + 4) = make_ushort4(s[4].x, s[5].x, s[6].x, s[7].x);
    *(ushort4*)(ol + ob)     = make_ushort4(s[0].y, s[1].y, s[2].y, s[3].y);
    *(ushort4*)(ol + ob + 4) = make_ushort4(s[4].y, s[5].y, s[6].y, s[7].y);
}

// ---------------- z2 aggregation (fp16 table [N][256]) + h2 epilogue ----------------
__global__ __launch_bounds__(256) void k_aggh(const u16* __restrict__ tbl,
                                              const int* __restrict__ offs,
                                              const int* __restrict__ ssrc,
                                              const float* __restrict__ inv,
                                              const float* __restrict__ y,
                                              const float* __restrict__ bias,
                                              u16* __restrict__ oh, u16* __restrict__ ol) {
    constexpr int U = 4;
    int wid = (blockIdx.x * 256 + threadIdx.x) >> 6;
    if (wid >= N_NODES) return;
    const int coff = blockIdx.y * 64;
    int lane = threadIdx.x & 63;
    int eg = lane >> 3;
    int cl = lane & 7;
    int beg = offs[wid], end = offs[wid + 1];
    float acc[8] = {};
    for (int e = beg + eg; e < end; e += U * 8) {
        int idx[U]; float msk[U];
#pragma unroll
        for (int j = 0; j < U; ++j) {
            int ee = e + j * 8;
            bool ok = ee < end;
            idx[j] = ssrc[ok ? ee : e];
            msk[j] = ok ? 1.f : 0.f;
        }
#pragma unroll
        for (int j = 0; j < U; ++j) {
            uint4 rv = *(const uint4*)(tbl + (size_t)idx[j] * 256 + coff + cl * 8);
            const __half2* hp = (const __half2*)&rv;
#pragma unroll
            for (int t = 0; t < 4; ++t) {
                float2 f = __half22float2(hp[t]);
                acc[t * 2 + 0] = fmaf(f.x, msk[j], acc[t * 2 + 0]);
                acc[t * 2 + 1] = fmaf(f.y, msk[j], acc[t * 2 + 1]);
            }
        }
    }
#pragma unroll
    for (int m = 8; m < 64; m <<= 1)
#pragma unroll
        for (int t = 0; t < 8; ++t) acc[t] += __shfl_xor(acc[t], m, 64);
    if (eg != 0) return;
    float wv = inv[wid];
    const size_t ob = (size_t)wid * 256 + coff + cl * 8;
    float4 y0 = *(const float4*)(y + ob);
    float4 y1 = *(const float4*)(y + ob + 4);
    float4 b0 = *(const float4*)(bias + coff + cl * 8);
    float4 b1 = *(const float4*)(bias + coff + cl * 8 + 4);
    float v[8];
    v[0] = leaky(acc[0] * wv + y0.x + b0.x);
    v[1] = leaky(acc[1] * wv + y0.y + b0.y);
    v[2] = leaky(acc[2] * wv + y0.z + b0.z);
    v[3] = leaky(acc[3] * wv + y0.w + b0.w);
    v[4] = leaky(acc[4] * wv + y1.x + b1.x);
    v[5] = leaky(acc[5] * wv + y1.y + b1.y);
    v[6] = leaky(acc[6] * wv + y1.z + b1.z);
    v[7] = leaky(acc[7] * wv + y1.w + b1.w);
    ushort2 s[8];
#pragma unroll
    for (int t = 0; t < 8; ++t) s[t] = split_bf(v[t]);
    *(ushort4*)(oh + ob)     = make_ushort4(s[0].x, s[1].x, s[2].x, s[3].x);
    *(ushort4*)(oh + ob + 4) = make_ushort4(s[4].x, s[5].x, s[6].x, s[7].x);
    *(ushort4*)(ol + ob)     = make_ushort4(s[0].y, s[1].y, s[2].y, s[3].y);
    *(ushort4*)(ol + ob + 4) = make_ushort4(s[4].y, s[5].y, s[6].y, s[7].y);
}

// ---------------- z3 aggregation (fp16 table [N][64]) + h3 epilogue ----------------
__global__ __launch_bounds__(256) void k_agg3h(const u16* __restrict__ tbl,
                                               const int* __restrict__ offs,
                                               const int* __restrict__ ssrc,
                                               const float* __restrict__ inv,
                                               const float* __restrict__ y,
                                               const float* __restrict__ bias,
                                               float* __restrict__ outf) {
    constexpr int U = 4;
    int wid = (blockIdx.x * 256 + threadIdx.x) >> 6;
    if (wid >= N_NODES) return;
    int lane = threadIdx.x & 63;
    int eg = lane >> 3;
    int cl = lane & 7;
    int beg = offs[wid], end = offs[wid + 1];
    float acc[8] = {};
    for (int e = beg + eg; e < end; e += U * 8) {
        int idx[U]; float msk[U];
#pragma unroll
        for (int j = 0; j < U; ++j) {
            int ee = e + j * 8;
            bool ok = ee < end;
            idx[j] = ssrc[ok ? ee : e];
            msk[j] = ok ? 1.f : 0.f;
        }
#pragma unroll
        for (int j = 0; j < U; ++j) {
            uint4 rv = *(const uint4*)(tbl + (size_t)idx[j] * 64 + cl * 8);
            const __half2* hp = (const __half2*)&rv;
#pragma unroll
            for (int t = 0; t < 4; ++t) {
                float2 f = __half22float2(hp[t]);
                acc[t * 2 + 0] = fmaf(f.x, msk[j], acc[t * 2 + 0]);
                acc[t * 2 + 1] = fmaf(f.y, msk[j], acc[t * 2 + 1]);
            }
        }
    }
#pragma unroll
    for (int m = 8; m < 64; m <<= 1)
#pragma unroll
        for (int t = 0; t < 8; ++t) acc[t] += __shfl_xor(acc[t], m, 64);
    if (eg != 0) return;
    float wv = inv[wid];
    const size_t ob = (size_t)wid * 64 + cl * 8;
    float4 y0 = *(const float4*)(y + ob);
    float4 y1 = *(const float4*)(y + ob + 4);
    float4 b0 = *(const float4*)(bias + cl * 8);
    float4 b1 = *(const float4*)(bias + cl * 8 + 4);
    *(float4*)(outf + ob) = make_float4(
        leaky(acc[0] * wv + y0.x + b0.x), leaky(acc[1] * wv + y0.y + b0.y),
        leaky(acc[2] * wv + y0.z + b0.z), leaky(acc[3] * wv + y0.w + b0.w));
    *(float4*)(outf + ob + 4) = make_float4(
        leaky(acc[4] * wv + y1.x + b1.x), leaky(acc[5] * wv + y1.y + b1.y),
        leaky(acc[6] * wv + y1.z + b1.z), leaky(acc[7] * wv + y1.w + b1.w));
}

// ---------------- split-bf16 MFMA GEMM: 128x128 tile, single-buffer, 4 blocks/CU ------
// (4 blocks/CU validated; 5 forces VGPR 64->48 and spills — round-12 regression.)
// mode1: 0 = f32 -> out1f; 1 = split planes -> out1h/out1l; 2 = fp16 -> out1h
__global__ __launch_bounds__(256, 4) void k_gemm_s(
    int M, int nct,
    const u16* __restrict__ A1h, const u16* __restrict__ A1l,
    const u16* __restrict__ B1h, const u16* __restrict__ B1l, int K1,
    const u16* __restrict__ A2h, const u16* __restrict__ A2l,
    const u16* __restrict__ B2h, const u16* __restrict__ B2l, int K2,
    const float* __restrict__ bias, int act, int colsplit, int mode1,
    float* __restrict__ out1f, u16* __restrict__ out1h, u16* __restrict__ out1l, int n1,
    float* __restrict__ out2f, int n2) {
    __shared__ u16 Ash[4096], Asl[4096], Bsh[4096], Bsl[4096];
    const int tid = threadIdx.x;
    const int lane = tid & 63;
    const int w = tid >> 6;
    const int wm = w & 1, wn = w >> 1;
    const int fr = lane & 15;
    const int q = lane >> 4;

    const int mT = (M + 127) >> 7;
    const int lin = blockIdx.x;
    const int grp = lin / (8 * nct);
    const int idx = lin - grp * (8 * nct);
    const int ct = idx >> 3;
    const int s8 = idx & 7;
    const int rowt = grp * 8 + s8;
    if (rowt >= mT) return;
    const int brow = rowt * 128;
    const int bcol = ct * 128;

    const int T1 = K1 >> 5, T = T1 + (K2 >> 5);

    const int c0 = (w * 2 + 0) * 64 + lane;
    const int c1 = (w * 2 + 1) * 64 + lane;
    const int r0 = c0 >> 2, g0 = (c0 & 3) ^ ((r0 >> 1) & 3);
    const int r1 = c1 >> 2, g1 = (c1 & 3) ^ ((r1 >> 1) & 3);
    int ar0 = brow + r0; if (ar0 >= M) ar0 = M - 1;
    int ar1 = brow + r1; if (ar1 >= M) ar1 = M - 1;
    const int br0 = bcol + r0, br1 = bcol + r1;
    const int ub0 = (w * 2 + 0) * 512;
    const int ub1 = (w * 2 + 1) * 512;

    f32x4 acc[4][4] = {};

    for (int kt = 0; kt < T; ++kt) {
        const u16 *Ah, *Al, *Bh, *Bl; int K, k0;
        if (kt < T1) { Ah = A1h; Al = A1l; Bh = B1h; Bl = B1l; K = K1; k0 = kt * 32; }
        else         { Ah = A2h; Al = A2l; Bh = B2h; Bl = B2l; K = K2; k0 = (kt - T1) * 32; }
        __syncthreads();
        {
            size_t ga0 = (size_t)ar0 * K + k0 + g0 * 8;
            size_t ga1 = (size_t)ar1 * K + k0 + g1 * 8;
            size_t gb0 = (size_t)br0 * K + k0 + g0 * 8;
            size_t gb1 = (size_t)br1 * K + k0 + g1 * 8;
            async_load16(Ah + ga0, &Ash[ub0]);
            async_load16(Ah + ga1, &Ash[ub1]);
            async_load16(Al + ga0, &Asl[ub0]);
            async_load16(Al + ga1, &Asl[ub1]);
            async_load16(Bh + gb0, &Bsh[ub0]);
            async_load16(Bh + gb1, &Bsh[ub1]);
            async_load16(Bl + gb0, &Bsl[ub0]);
            async_load16(Bl + gb1, &Bsl[ub1]);
        }
        __syncthreads();
        bf16x8 fah[4], fal[4], fbh[4], fbl[4];
#pragma unroll
        for (int rt = 0; rt < 4; ++rt) {
            int row = wm * 64 + rt * 16 + fr;
            int ad = row * 32 + ((q ^ ((row >> 1) & 3)) * 8);
            fah[rt] = __builtin_bit_cast(bf16x8, *(const uint4*)&Ash[ad]);
            fal[rt] = __builtin_bit_cast(bf16x8, *(const uint4*)&Asl[ad]);
        }
#pragma unroll
        for (int ctf = 0; ctf < 4; ++ctf) {
            int row = wn * 64 + ctf * 16 + fr;
            int ad = row * 32 + ((q ^ ((row >> 1) & 3)) * 8);
            fbh[ctf] = __builtin_bit_cast(bf16x8, *(const uint4*)&Bsh[ad]);
            fbl[ctf] = __builtin_bit_cast(bf16x8, *(const uint4*)&Bsl[ad]);
        }
#pragma unroll
        for (int rt = 0; rt < 4; ++rt)
#pragma unroll
            for (int ctf = 0; ctf < 4; ++ctf) {
                acc[rt][ctf] = __builtin_amdgcn_mfma_f32_16x16x32_bf16(fah[rt], fbh[ctf], acc[rt][ctf], 0, 0, 0);
                acc[rt][ctf] = __builtin_amdgcn_mfma_f32_16x16x32_bf16(fah[rt], fbl[ctf], acc[rt][ctf], 0, 0, 0);
                acc[rt][ctf] = __builtin_amdgcn_mfma_f32_16x16x32_bf16(fal[rt], fbh[ctf], acc[rt][ctf], 0, 0, 0);
            }
    }

#pragma unroll
    for (int rt = 0; rt < 4; ++rt) {
        int rowb = brow + wm * 64 + rt * 16 + q * 4;
#pragma unroll
        for (int ctf = 0; ctf < 4; ++ctf) {
            int col = bcol + wn * 64 + ctf * 16 + fr;
            float b = bias ? bias[col] : 0.f;
#pragma unroll
            for (int r = 0; r < 4; ++r) {
                int row = rowb + r;
                if (row >= M) continue;
                float v = acc[rt][ctf][r] + b;
                if (act) v = leaky(v);
                if (col < colsplit) {
                    if (mode1 == 0) {
                        out1f[(size_t)row * n1 + col] = v;
                    } else if (mode1 == 1) {
                        ushort2 s = split_bf(v);
                        out1h[(size_t)row * n1 + col] = s.x;
                        out1l[(size_t)row * n1 + col] = s.y;
                    } else {
                        __half hv = __float2half(v);
                        out1h[(size_t)row * n1 + col] = __builtin_bit_cast(u16, hv);
                    }
                } else {
                    out2f[(size_t)row * n2 + (col - colsplit)] = v;
                }
            }
        }
    }
}

// ---------------- fused head: h3 -> pre_fc -> leaky(fc1) -> fc2 ------
__global__ __launch_bounds__(256) void k_head(const float* __restrict__ h3,
                                              const float* __restrict__ Wp, const float* __restrict__ bp,
                                              const float* __restrict__ Wf1, const float* __restrict__ bf1,
                                              const float* __restrict__ Wf2, const float* __restrict__ bf2,
                                              float* __restrict__ out) {
    __shared__ float sWp[64 * 32], sW1[32 * 32], sW2[32 * 2];
    __shared__ float sbp[32], sb1[32], sb2[2];
    int tid = threadIdx.x;
    for (int i = tid; i < 64 * 32; i += 256) sWp[i] = Wp[i];
    for (int i = tid; i < 32 * 32; i += 256) sW1[i] = Wf1[i];
    for (int i = tid; i < 64; i += 256) sW2[i] = Wf2[i];
    if (tid < 32) { sbp[tid] = bp[tid]; sb1[tid] = bf1[tid]; }
    if (tid < 2) sb2[tid] = bf2[tid];
    __syncthreads();
    int row = blockIdx.x * 256 + tid;
    if (row >= N_NODES) return;
    const float4* h4v = (const float4*)(h3 + (size_t)row * 64);
    float xr[64];
#pragma unroll
    for (int i = 0; i < 16; ++i) {
        float4 v = h4v[i];
        xr[i * 4 + 0] = v.x; xr[i * 4 + 1] = v.y;
        xr[i * 4 + 2] = v.z; xr[i * 4 + 3] = v.w;
    }
    float h4[32];
    for (int o = 0; o < 32; ++o) {
        float s = sbp[o];
#pragma unroll
        for (int i = 0; i < 64; ++i) s += xr[i] * sWp[i * 32 + o];
        h4[o] = s;
    }
    float h5[32];
    for (int o = 0; o < 32; ++o) {
        float s = sb1[o];
#pragma unroll
        for (int i = 0; i < 32; ++i) s += h4[i] * sW1[i * 32 + o];
        h5[o] = leaky(s);
    }
#pragma unroll
    for (int o = 0; o < 2; ++o) {
        float s = sb2[o];
#pragma unroll
        for (int i = 0; i < 32; ++i) s += h5[i] * sW2[i * 2 + o];
        out[(size_t)row * 2 + o] = s;
    }
}

// ---------------- launch ----------------
extern "C" void kernel_launch(void* const* d_in, const int* in_sizes, int n_in,
                              void* d_out, int out_size, void* d_ws, size_t ws_size,
                              hipStream_t stream) {
    const float* x   = (const float*)d_in[0];
    const int*   ei  = (const int*)d_in[1];
    const float* W1l = (const float*)d_in[5];
    const float* b1  = (const float*)d_in[6];
    const float* W1r = (const float*)d_in[7];
    const float* W2l = (const float*)d_in[8];
    const float* b2  = (const float*)d_in[9];
    const float* W2r = (const float*)d_in[10];
    const float* W3l = (const float*)d_in[11];
    const float* b3  = (const float*)d_in[12];
    const float* W3r = (const float*)d_in[13];
    const float* Wp  = (const float*)d_in[14];
    const float* bp  = (const float*)d_in[15];
    const float* Wf1 = (const float*)d_in[16];
    const float* bf1 = (const float*)d_in[17];
    const float* Wf2 = (const float*)d_in[18];
    const float* bf2 = (const float*)d_in[19];
    float* out = (float*)d_out;
    (void)in_sizes; (void)n_in; (void)out_size; (void)ws_size;

    const int* src = ei;
    const int* dst = ei + N_EDGES;

    char* base = (char*)d_ws;
    size_t off = 0;
    auto alloc = [&](size_t bytes) -> void* {
        void* r = base + off;
        off = (off + bytes + 255) & ~(size_t)255;
        return r;
    };
    const size_t NN = N_NODES;
    int*   cnt    = (int*)alloc(NN * 4);
    int*   offs   = (int*)alloc((NN + 1) * 4);
    int*   cursor = (int*)alloc(NN * 4);
    float* inv    = (float*)alloc(NN * 4);
    int*   bsum   = (int*)alloc(64 * 4);
    int*   ssrc   = (int*)alloc((size_t)N_EDGES * 4);
    u16* w1lh = (u16*)alloc(128 * 512 * 2); u16* w1ll = (u16*)alloc(128 * 512 * 2);
    u16* w1rh = (u16*)alloc(128 * 512 * 2); u16* w1rl = (u16*)alloc(128 * 512 * 2);
    u16* w2ch = (u16*)alloc(512 * 512 * 2); u16* w2cl = (u16*)alloc(512 * 512 * 2);
    u16* w3ch = (u16*)alloc(128 * 256 * 2); u16* w3cl = (u16*)alloc(128 * 256 * 2);

    // Live-range-aliased regions (~205 MB)
    char* regA = (char*)alloc(NN * 256 * 4);       // xh|xl|axh|axl -> z2h(fp16) -> h3
    char* regB = (char*)alloc(NN * 512 * 2 * 2);   // h1h|h1l -> h2h|h2l
    char* regD = (char*)alloc(NN * 256 * 4);       // y2 -> z3h|y3

    u16* xh  = (u16*)regA;
    u16* xl  = xh + NN * 128;
    u16* axh = xl + NN * 128;
    u16* axl = axh + NN * 128;
    u16* h1h = (u16*)regB;
    u16* h1l = h1h + NN * 512;
    u16* z2h = (u16*)regA;                         // fp16 z2 [N][256] (x/aggX dead)
    u16* h2h = (u16*)regB;                         // aggh epilogue out (h1 dead)
    u16* h2l = h2h + NN * 256;
    float* y2f = (float*)regD;                     // read inside aggh epilogue (then dead)
    u16*   z3h = (u16*)regD;                       // fp16 z3 [N][64] (y2 dead)
    float* y3f = (float*)(regD + NN * 64 * 2);     // f32 y3 [N][64]
    float* h3f = (float*)regA;                     // agg3 epilogue out (z2h dead)

    // CSR + prep
    hipMemsetAsync(cnt, 0, NN * 4, stream);
    k_prep<<<3125 + 6250 + 1664, 256, 0, stream>>>(dst, cnt, x, xh, xl,
        W1l, W1r, W2l, W2r, W3l, W3r,
        w1lh, w1ll, w1rh, w1rl, w2ch, w2cl, w3ch, w3cl);
    const int nb = (N_NODES + 1023) / 1024;   // 49
    k_scan1<<<nb, 1024, 0, stream>>>(cnt, offs, bsum);
    k_scan3<<<(N_NODES + 255) / 256, 256, 0, stream>>>(cnt, offs, cursor, inv, bsum, nb);
    k_fill<<<(N_EDGES + 255) / 256, 256, 0, stream>>>(src, dst, cursor, ssrc);

    const int aggGrid = (N_NODES + 3) / 4;             // 12500
    const int mT = (N_NODES + 127) / 128;              // 391
    const int grid4 = ((mT + 7) / 8) * 32;             // nct=4
    const int grid1 = ((mT + 7) / 8) * 8;              // nct=1

    // layer 1: aggX = S x via bf16-plane gather (2 chunks); h1 = leaky(aggX@W1l + x@W1r + b1)
    k_aggb<<<dim3(aggGrid, 2), 256, 0, stream>>>(
        xh, xl, offs, ssrc, inv, axh, axl);
    k_gemm_s<<<grid4, 256, 0, stream>>>(N_NODES, 4,
        axh, axl, w1lh, w1ll, 128, xh, xl, w1rh, w1rl, 128,
        b1, 1, 512, 1, nullptr, h1h, h1l, 512, nullptr, 0);

    // layer 2: [z2(fp16)|y2(f32)] = h1 @ [W2l|W2r]; aggh: h2 = leaky(S z2 + y2 + b2)
    k_gemm_s<<<grid4, 256, 0, stream>>>(N_NODES, 4,
        h1h, h1l, w2ch, w2cl, 512, nullptr, nullptr, nullptr, nullptr, 0,
        nullptr, 0, 256, 2, nullptr, z2h, nullptr, 256, y2f, 256);
    k_aggh<<<dim3(aggGrid, 4), 256, 0, stream>>>(
        z2h, offs, ssrc, inv, y2f, b2, h2h, h2l);

    // layer 3: [z3(fp16)|y3(f32)] = h2 @ [W3l|W3r]; agg3: h3 = leaky(S z3 + y3 + b3)
    k_gemm_s<<<grid1, 256, 0, stream>>>(N_NODES, 1,
        h2h, h2l, w3ch, w3cl, 256, nullptr, nullptr, nullptr, nullptr, 0,
        nullptr, 0, 64, 2, nullptr, z3h, nullptr, 64, y3f, 64);
    k_agg3h<<<aggGrid, 256, 0, stream>>>(
        z3h, offs, ssrc, inv, y3f, b3, h3f);

    // head: h3 -> pre_fc -> leaky(fc1) -> fc2
    k_head<<<(N_NODES + 255) / 256, 256, 0, stream>>>(h3f,
        Wp, bp, Wf1, bf1, Wf2, bf2, out);
}

// Round 15
// 466.934 us; speedup vs baseline: 1.8631x; 1.2627x over previous
//
#include <hip/hip_runtime.h>
#include <hip/hip_fp16.h>

#define N_NODES 50000
#define N_EDGES 800000
#define SLOPE 0.15f

typedef unsigned short u16;
typedef __attribute__((ext_vector_type(8))) _Float16 f16x8;
typedef __attribute__((ext_vector_type(4))) float f32x4;

static __device__ __forceinline__ float leaky(float v) { return v > 0.f ? v : SLOPE * v; }

static __device__ __forceinline__ u16 f2h(float v) {
    return __builtin_bit_cast(u16, __float2half(v));
}

// async global->LDS 16B: HW writes lane's data to (wave-uniform lds base) + lane*16
static __device__ __forceinline__ void async_load16(const u16* g, u16* l) {
    __builtin_amdgcn_global_load_lds(
        (const __attribute__((address_space(1))) unsigned int*)g,
        (__attribute__((address_space(3))) unsigned int*)l, 16, 0, 0);
}

// ---------------- merged prep: edge count | x->fp16 | weight transpose->fp16 ----------
// block ranges: [0,3125) count; [3125,9375) xconv; [9375,11039) wconv
__global__ void k_prep(const int* __restrict__ dst, int* __restrict__ cnt,
                       const float* __restrict__ x, u16* __restrict__ xp,
                       const float* __restrict__ W1l, const float* __restrict__ W1r,
                       const float* __restrict__ W2l, const float* __restrict__ W2r,
                       const float* __restrict__ W3l, const float* __restrict__ W3r,
                       u16* w1lp, u16* w1rp, u16* w2cp, u16* w3cp) {
    int b = blockIdx.x, tid = threadIdx.x;
    if (b < 3125) {
        int e = b * 256 + tid;
        if (e < N_EDGES) atomicAdd(&cnt[dst[e]], 1);
        return;
    }
    b -= 3125;
    if (b < 6250) {
        int i = b * 256 + tid;
        if (i >= N_NODES * 32) return;
        float4 v = ((const float4*)x)[i];
        ((ushort4*)xp)[i] = make_ushort4(f2h(v.x), f2h(v.y), f2h(v.z), f2h(v.w));
        return;
    }
    b -= 6250;
    const float* W; u16* op; int K, N;
    if (b < 256)       { W = W1l; op = w1lp; K = 128; N = 512; }
    else if (b < 512)  { W = W1r; op = w1rp; K = 128; N = 512; b -= 256; }
    else if (b < 1024) { W = W2l; op = w2cp; K = 512; N = 256; b -= 512; }
    else if (b < 1536) { W = W2r; op = w2cp + 256 * 512; K = 512; N = 256; b -= 1024; }
    else if (b < 1600) { W = W3l; op = w3cp; K = 256; N = 64; b -= 1536; }
    else               { W = W3r; op = w3cp + 64 * 256; K = 256; N = 64; b -= 1600; }
    int i = b * 256 + tid;
    if (i >= K * N) return;
    int k = i / N, n = i - k * N;
    op[(size_t)n * K + k] = f2h(W[i]);   // W^T [N][K] fp16
}

// multi-block scan, stage 1
__global__ __launch_bounds__(1024) void k_scan1(const int* __restrict__ cnt,
                                                int* __restrict__ offs,
                                                int* __restrict__ bsum) {
    __shared__ int wsum[16];
    int tid = threadIdx.x, lane = tid & 63, wv = tid >> 6;
    int i = blockIdx.x * 1024 + tid;
    int orig = (i < N_NODES) ? cnt[i] : 0;
    int v = orig;
#pragma unroll
    for (int d = 1; d < 64; d <<= 1) {
        int t = __shfl_up(v, d, 64);
        if (lane >= d) v += t;
    }
    if (lane == 63) wsum[wv] = v;
    __syncthreads();
    if (wv == 0) {
        int s = (lane < 16) ? wsum[lane] : 0;
#pragma unroll
        for (int d = 1; d < 16; d <<= 1) {
            int t = __shfl_up(s, d, 64);
            if (lane >= d) s += t;
        }
        if (lane < 16) wsum[lane] = s;
        if (lane == 15) bsum[blockIdx.x] = s;
    }
    __syncthreads();
    int wpre = (wv == 0) ? 0 : wsum[wv - 1];
    if (i < N_NODES) offs[i] = v + wpre - orig;
}

// stage 2+3 merged
__global__ void k_scan3(const int* __restrict__ cnt, int* __restrict__ offs,
                        int* __restrict__ cursor, float* __restrict__ inv,
                        const int* __restrict__ bsum, int nb) {
    __shared__ int sb[64];
    int tid = threadIdx.x;
    if (tid < 64) {
        int v = (tid < nb) ? bsum[tid] : 0;
        int s = v;
#pragma unroll
        for (int d = 1; d < 64; d <<= 1) {
            int t = __shfl_up(s, d, 64);
            if (tid >= d) s += t;
        }
        sb[tid] = s - v;
    }
    __syncthreads();
    int i = blockIdx.x * 256 + tid;
    if (i >= N_NODES) return;
    int c = cnt[i];
    int o = offs[i] + sb[i >> 10];
    offs[i] = o;
    cursor[i] = o;
    inv[i] = 1.0f / (float)(c > 1 ? c : 1);
    if (i == 0) offs[N_NODES] = N_EDGES;
}

__global__ void k_fill(const int* __restrict__ src, const int* __restrict__ dst,
                       int* __restrict__ cursor, int* __restrict__ ssrc) {
    int e = blockIdx.x * 256 + threadIdx.x;
    if (e < N_EDGES) {
        int pos = atomicAdd(&cursor[dst[e]], 1);
        ssrc[pos] = src[e];
    }
}

// ---------------- fp16-table mean aggregation, 64-col chunks ----------------
// 8 lanes/edge x 8 halves; U=4 masked unroll; blockIdx.y = column chunk.
// EPI: 0 = a -> fp16 outh; 2 = leaky(a+y+bias) -> fp16 outh; 3 = leaky(a+y+bias) -> f32 outf
template <int STRIDE, int EPI>
__global__ __launch_bounds__(256) void k_aggf(const u16* __restrict__ tbl,
                                              const int* __restrict__ offs,
                                              const int* __restrict__ ssrc,
                                              const float* __restrict__ inv,
                                              const u16* __restrict__ y,
                                              const float* __restrict__ bias,
                                              u16* __restrict__ outh,
                                              float* __restrict__ outf) {
    constexpr int U = 4;
    int wid = (blockIdx.x * 256 + threadIdx.x) >> 6;
    if (wid >= N_NODES) return;
    const int coff = blockIdx.y * 64;
    int lane = threadIdx.x & 63;
    int eg = lane >> 3;
    int cl = lane & 7;
    int beg = offs[wid], end = offs[wid + 1];
    float acc[8] = {};
    for (int e = beg + eg; e < end; e += U * 8) {
        int idx[U]; float msk[U];
#pragma unroll
        for (int j = 0; j < U; ++j) {
            int ee = e + j * 8;
            bool ok = ee < end;
            idx[j] = ssrc[ok ? ee : e];
            msk[j] = ok ? 1.f : 0.f;
        }
#pragma unroll
        for (int j = 0; j < U; ++j) {
            uint4 rv = *(const uint4*)(tbl + (size_t)idx[j] * STRIDE + coff + cl * 8);
            const __half2* hp = (const __half2*)&rv;
#pragma unroll
            for (int t = 0; t < 4; ++t) {
                float2 f = __half22float2(hp[t]);
                acc[t * 2 + 0] = fmaf(f.x, msk[j], acc[t * 2 + 0]);
                acc[t * 2 + 1] = fmaf(f.y, msk[j], acc[t * 2 + 1]);
            }
        }
    }
#pragma unroll
    for (int m = 8; m < 64; m <<= 1)
#pragma unroll
        for (int t = 0; t < 8; ++t) acc[t] += __shfl_xor(acc[t], m, 64);
    if (eg != 0) return;
    float wv = inv[wid];
    const size_t ob = (size_t)wid * STRIDE + coff + cl * 8;
    float v[8];
    if (EPI == 0) {
#pragma unroll
        for (int t = 0; t < 8; ++t) v[t] = acc[t] * wv;
    } else {
        uint4 yv4 = *(const uint4*)(y + ob);
        const __half2* yp = (const __half2*)&yv4;
        float4 b0 = *(const float4*)(bias + coff + cl * 8);
        float4 b1 = *(const float4*)(bias + coff + cl * 8 + 4);
        float bb[8] = {b0.x, b0.y, b0.z, b0.w, b1.x, b1.y, b1.z, b1.w};
#pragma unroll
        for (int t = 0; t < 4; ++t) {
            float2 f = __half22float2(yp[t]);
            v[t * 2 + 0] = leaky(acc[t * 2 + 0] * wv + f.x + bb[t * 2 + 0]);
            v[t * 2 + 1] = leaky(acc[t * 2 + 1] * wv + f.y + bb[t * 2 + 1]);
        }
    }
    if (EPI == 3) {
        *(float4*)(outf + ob)     = make_float4(v[0], v[1], v[2], v[3]);
        *(float4*)(outf + ob + 4) = make_float4(v[4], v[5], v[6], v[7]);
    } else {
        *(ushort4*)(outh + ob)     = make_ushort4(f2h(v[0]), f2h(v[1]), f2h(v[2]), f2h(v[3]));
        *(ushort4*)(outh + ob + 4) = make_ushort4(f2h(v[4]), f2h(v[5]), f2h(v[6]), f2h(v[7]));
    }
}

// ---------------- fp16 MFMA GEMM: 128x128 tile, single-buffer, 4 blocks/CU ------
// C = A1@B1 [+ A2@B2] (+bias, act); single mfma_f32_16x16x32_f16 per frag pair.
// B pre-transposed fp16 [N][K]. Outputs fp16: cols<colsplit -> out1h (n1) else out2h (n2).
__global__ __launch_bounds__(256, 4) void k_gemm_f(
    int M, int nct,
    const u16* __restrict__ A1, const u16* __restrict__ B1, int K1,
    const u16* __restrict__ A2, const u16* __restrict__ B2, int K2,
    const float* __restrict__ bias, int act, int colsplit,
    u16* __restrict__ out1h, int n1, u16* __restrict__ out2h, int n2) {
    __shared__ u16 Ash[4096], Bsh[4096];
    const int tid = threadIdx.x;
    const int lane = tid & 63;
    const int w = tid >> 6;
    const int wm = w & 1, wn = w >> 1;
    const int fr = lane & 15;
    const int q = lane >> 4;

    const int mT = (M + 127) >> 7;
    const int lin = blockIdx.x;
    const int grp = lin / (8 * nct);
    const int idx = lin - grp * (8 * nct);
    const int ct = idx >> 3;
    const int s8 = idx & 7;
    const int rowt = grp * 8 + s8;
    if (rowt >= mT) return;
    const int brow = rowt * 128;
    const int bcol = ct * 128;

    const int T1 = K1 >> 5, T = T1 + (K2 >> 5);

    const int c0 = (w * 2 + 0) * 64 + lane;
    const int c1 = (w * 2 + 1) * 64 + lane;
    const int r0 = c0 >> 2, g0 = (c0 & 3) ^ ((r0 >> 1) & 3);
    const int r1 = c1 >> 2, g1 = (c1 & 3) ^ ((r1 >> 1) & 3);
    int ar0 = brow + r0; if (ar0 >= M) ar0 = M - 1;
    int ar1 = brow + r1; if (ar1 >= M) ar1 = M - 1;
    const int br0 = bcol + r0, br1 = bcol + r1;
    const int ub0 = (w * 2 + 0) * 512;
    const int ub1 = (w * 2 + 1) * 512;

    f32x4 acc[4][4] = {};

    for (int kt = 0; kt < T; ++kt) {
        const u16 *A, *B; int K, k0;
        if (kt < T1) { A = A1; B = B1; K = K1; k0 = kt * 32; }
        else         { A = A2; B = B2; K = K2; k0 = (kt - T1) * 32; }
        __syncthreads();
        {
            size_t ga0 = (size_t)ar0 * K + k0 + g0 * 8;
            size_t ga1 = (size_t)ar1 * K + k0 + g1 * 8;
            size_t gb0 = (size_t)br0 * K + k0 + g0 * 8;
            size_t gb1 = (size_t)br1 * K + k0 + g1 * 8;
            async_load16(A + ga0, &Ash[ub0]);
            async_load16(A + ga1, &Ash[ub1]);
            async_load16(B + gb0, &Bsh[ub0]);
            async_load16(B + gb1, &Bsh[ub1]);
        }
        __syncthreads();
        f16x8 fa[4], fb[4];
#pragma unroll
        for (int rt = 0; rt < 4; ++rt) {
            int row = wm * 64 + rt * 16 + fr;
            int ad = row * 32 + ((q ^ ((row >> 1) & 3)) * 8);
            fa[rt] = __builtin_bit_cast(f16x8, *(const uint4*)&Ash[ad]);
        }
#pragma unroll
        for (int ctf = 0; ctf < 4; ++ctf) {
            int row = wn * 64 + ctf * 16 + fr;
            int ad = row * 32 + ((q ^ ((row >> 1) & 3)) * 8);
            fb[ctf] = __builtin_bit_cast(f16x8, *(const uint4*)&Bsh[ad]);
        }
#pragma unroll
        for (int rt = 0; rt < 4; ++rt)
#pragma unroll
            for (int ctf = 0; ctf < 4; ++ctf)
                acc[rt][ctf] = __builtin_amdgcn_mfma_f32_16x16x32_f16(fa[rt], fb[ctf], acc[rt][ctf], 0, 0, 0);
    }

    // epilogue: frag C/D layout col=lane&15, row=q*4+reg  [m89]
#pragma unroll
    for (int rt = 0; rt < 4; ++rt) {
        int rowb = brow + wm * 64 + rt * 16 + q * 4;
#pragma unroll
        for (int ctf = 0; ctf < 4; ++ctf) {
            int col = bcol + wn * 64 + ctf * 16 + fr;
            float b = bias ? bias[col] : 0.f;
#pragma unroll
            for (int r = 0; r < 4; ++r) {
                int row = rowb + r;
                if (row >= M) continue;
                float v = acc[rt][ctf][r] + b;
                if (act) v = leaky(v);
                if (col < colsplit) out1h[(size_t)row * n1 + col] = f2h(v);
                else                out2h[(size_t)row * n2 + (col - colsplit)] = f2h(v);
            }
        }
    }
}

// ---------------- fused head: h3 -> pre_fc -> leaky(fc1) -> fc2 ------
__global__ __launch_bounds__(256) void k_head(const float* __restrict__ h3,
                                              const float* __restrict__ Wp, const float* __restrict__ bp,
                                              const float* __restrict__ Wf1, const float* __restrict__ bf1,
                                              const float* __restrict__ Wf2, const float* __restrict__ bf2,
                                              float* __restrict__ out) {
    __shared__ float sWp[64 * 32], sW1[32 * 32], sW2[32 * 2];
    __shared__ float sbp[32], sb1[32], sb2[2];
    int tid = threadIdx.x;
    for (int i = tid; i < 64 * 32; i += 256) sWp[i] = Wp[i];
    for (int i = tid; i < 32 * 32; i += 256) sW1[i] = Wf1[i];
    for (int i = tid; i < 64; i += 256) sW2[i] = Wf2[i];
    if (tid < 32) { sbp[tid] = bp[tid]; sb1[tid] = bf1[tid]; }
    if (tid < 2) sb2[tid] = bf2[tid];
    __syncthreads();
    int row = blockIdx.x * 256 + tid;
    if (row >= N_NODES) return;
    const float4* h4v = (const float4*)(h3 + (size_t)row * 64);
    float xr[64];
#pragma unroll
    for (int i = 0; i < 16; ++i) {
        float4 v = h4v[i];
        xr[i * 4 + 0] = v.x; xr[i * 4 + 1] = v.y;
        xr[i * 4 + 2] = v.z; xr[i * 4 + 3] = v.w;
    }
    float h4[32];
    for (int o = 0; o < 32; ++o) {
        float s = sbp[o];
#pragma unroll
        for (int i = 0; i < 64; ++i) s += xr[i] * sWp[i * 32 + o];
        h4[o] = s;
    }
    float h5[32];
    for (int o = 0; o < 32; ++o) {
        float s = sb1[o];
#pragma unroll
        for (int i = 0; i < 32; ++i) s += h4[i] * sW1[i * 32 + o];
        h5[o] = leaky(s);
    }
#pragma unroll
    for (int o = 0; o < 2; ++o) {
        float s = sb2[o];
#pragma unroll
        for (int i = 0; i < 32; ++i) s += h5[i] * sW2[i * 2 + o];
        out[(size_t)row * 2 + o] = s;
    }
}

// ---------------- launch ----------------
extern "C" void kernel_launch(void* const* d_in, const int* in_sizes, int n_in,
                              void* d_out, int out_size, void* d_ws, size_t ws_size,
                              hipStream_t stream) {
    const float* x   = (const float*)d_in[0];
    const int*   ei  = (const int*)d_in[1];
    const float* W1l = (const float*)d_in[5];
    const float* b1  = (const float*)d_in[6];
    const float* W1r = (const float*)d_in[7];
    const float* W2l = (const float*)d_in[8];
    const float* b2  = (const float*)d_in[9];
    const float* W2r = (const float*)d_in[10];
    const float* W3l = (const float*)d_in[11];
    const float* b3  = (const float*)d_in[12];
    const float* W3r = (const float*)d_in[13];
    const float* Wp  = (const float*)d_in[14];
    const float* bp  = (const float*)d_in[15];
    const float* Wf1 = (const float*)d_in[16];
    const float* bf1 = (const float*)d_in[17];
    const float* Wf2 = (const float*)d_in[18];
    const float* bf2 = (const float*)d_in[19];
    float* out = (float*)d_out;
    (void)in_sizes; (void)n_in; (void)out_size; (void)ws_size;

    const int* src = ei;
    const int* dst = ei + N_EDGES;

    char* base = (char*)d_ws;
    size_t off = 0;
    auto alloc = [&](size_t bytes) -> void* {
        void* r = base + off;
        off = (off + bytes + 255) & ~(size_t)255;
        return r;
    };
    const size_t NN = N_NODES;
    int*   cnt    = (int*)alloc(NN * 4);
    int*   offs   = (int*)alloc((NN + 1) * 4);
    int*   cursor = (int*)alloc(NN * 4);
    float* inv    = (float*)alloc(NN * 4);
    int*   bsum   = (int*)alloc(64 * 4);
    int*   ssrc   = (int*)alloc((size_t)N_EDGES * 4);
    u16* w1lp = (u16*)alloc(128 * 512 * 2);
    u16* w1rp = (u16*)alloc(128 * 512 * 2);
    u16* w2cp = (u16*)alloc(512 * 512 * 2);
    u16* w3cp = (u16*)alloc(128 * 256 * 2);
    // all activations single-plane fp16 (except h3 f32); total ~185 MB, no aliasing
    u16* xp  = (u16*)alloc(NN * 128 * 2);
    u16* axp = (u16*)alloc(NN * 128 * 2);
    u16* h1p = (u16*)alloc(NN * 512 * 2);
    u16* z2h = (u16*)alloc(NN * 256 * 2);
    u16* y2h = (u16*)alloc(NN * 256 * 2);
    u16* h2p = (u16*)alloc(NN * 256 * 2);
    u16* z3h = (u16*)alloc(NN * 64 * 2);
    u16* y3h = (u16*)alloc(NN * 64 * 2);
    float* h3f = (float*)alloc(NN * 64 * 4);

    // CSR + prep
    hipMemsetAsync(cnt, 0, NN * 4, stream);
    k_prep<<<3125 + 6250 + 1664, 256, 0, stream>>>(dst, cnt, x, xp,
        W1l, W1r, W2l, W2r, W3l, W3r, w1lp, w1rp, w2cp, w3cp);
    const int nb = (N_NODES + 1023) / 1024;   // 49
    k_scan1<<<nb, 1024, 0, stream>>>(cnt, offs, bsum);
    k_scan3<<<(N_NODES + 255) / 256, 256, 0, stream>>>(cnt, offs, cursor, inv, bsum, nb);
    k_fill<<<(N_EDGES + 255) / 256, 256, 0, stream>>>(src, dst, cursor, ssrc);

    const int aggGrid = (N_NODES + 3) / 4;             // 12500
    const int mT = (N_NODES + 127) / 128;              // 391
    const int grid4 = ((mT + 7) / 8) * 32;             // nct=4
    const int grid1 = ((mT + 7) / 8) * 8;              // nct=1

    // layer 1: aggX = S x (fp16 gather, 2 chunks); h1 = leaky(aggX@W1l + x@W1r + b1) (fp16)
    k_aggf<128, 0><<<dim3(aggGrid, 2), 256, 0, stream>>>(
        xp, offs, ssrc, inv, nullptr, nullptr, axp, nullptr);
    k_gemm_f<<<grid4, 256, 0, stream>>>(N_NODES, 4,
        axp, w1lp, 128, xp, w1rp, 128, b1, 1, 512, h1p, 512, nullptr, 0);

    // layer 2: [z2|y2] = h1 @ [W2l|W2r] (fp16); h2 = leaky(S z2 + y2 + b2) (fp16)
    k_gemm_f<<<grid4, 256, 0, stream>>>(N_NODES, 4,
        h1p, w2cp, 512, nullptr, nullptr, 0, nullptr, 0, 256, z2h, 256, y2h, 256);
    k_aggf<256, 2><<<dim3(aggGrid, 4), 256, 0, stream>>>(
        z2h, offs, ssrc, inv, y2h, b2, h2p, nullptr);

    // layer 3: [z3|y3] = h2 @ [W3l|W3r] (fp16); h3 = leaky(S z3 + y3 + b3) (f32)
    k_gemm_f<<<grid1, 256, 0, stream>>>(N_NODES, 1,
        h2p, w3cp, 256, nullptr, nullptr, 0, nullptr, 0, 64, z3h, 64, y3h, 64);
    k_aggf<64, 3><<<dim3(aggGrid, 1), 256, 0, stream>>>(
        z3h, offs, ssrc, inv, y3h, b3, nullptr, h3f);

    // head: h3 -> pre_fc -> leaky(fc1) -> fc2
    k_head<<<(N_NODES + 255) / 256, 256, 0, stream>>>(h3f,
        Wp, bp, Wf1, bf1, Wf2, bf2, out);
}